// Round 8
// baseline (437.762 us; speedup 1.0000x reference)
//
#include <hip/hip_runtime.h>
#include <hip/hip_fp16.h>

// SelfAttention: B=8, C=64, N=4096, d_head=8.
// o[b,c,m] = gamma * sum_n h[b,c,n] * softmax_n(f[:,n].g[:,m]) + x[b,c,m]
// R8 = R7 with the inline-asm v_exp_f32 replaced by __builtin_amdgcn_exp2f
// (TRANS-op hazard: inline asm bypasses the compiler's wait-state insertion,
// dependent VALU read stale VGPR bits -> NaN). Packed f-frag records,
// consume-then-prefetch, unnormalized partials + invL merge, W-row proj.

typedef _Float16 half8_t __attribute__((ext_vector_type(8)));
typedef _Float16 half4_t __attribute__((ext_vector_type(4)));
typedef _Float16 half2_t __attribute__((ext_vector_type(2)));
typedef __fp16  fp16x2  __attribute__((ext_vector_type(2)));
typedef float float4_t __attribute__((ext_vector_type(4)));

#define NTOK 4096
#define PRH 72   // LDS h-row stride in halves (144 B: 16B-aligned, bank-rotating)
#define LOG2E 1.44269504088896340736f

#if __has_builtin(__builtin_amdgcn_exp2f)
__device__ __forceinline__ float fexp2(float x) { return __builtin_amdgcn_exp2f(x); }
#else
__device__ __forceinline__ float fexp2(float x) { return exp2f(x); }
#endif

__device__ __forceinline__ half2_t pkcvt(float a, float b) {
    fp16x2 v = __builtin_amdgcn_cvt_pkrtz(a, b);
    return __builtin_bit_cast(half2_t, v);
}

// ---------------- projection -------------------------------------------------
// grid (64 key-tiles, 8 b, 5 og), block = 1 wave (lane = column in tile).
// og 0: fTR packed frag records [b][kt*16+ml][q<2][t4][4] (log2e folded) +
//       gT16[col][16] = {g, -M_col, 0...}.  og 1..4: h channels (fp16 c-major).
// W loops are j-outer so each W row is a contiguous 256-B scalar stream.
__global__ __launch_bounds__(64, 4) void proj_kernel(
    const float* __restrict__ x,
    const float* __restrict__ Wq, const float* __restrict__ bq,
    const float* __restrict__ Wk, const float* __restrict__ bk,
    const float* __restrict__ Wv, const float* __restrict__ bv,
    __half* __restrict__ fTR, __half* __restrict__ gT16, __half* __restrict__ hM)
{
    const int lane = threadIdx.x;
    const int kt   = blockIdx.x;
    const int b    = blockIdx.y;
    const int og   = blockIdx.z;
    const int n    = kt * 64 + lane;

    float xv[64];
    const float* xb = x + (((size_t)b * 64) << 12) + n;
#pragma unroll
    for (int c = 0; c < 64; c++) xv[c] = xb[(size_t)c << 12];

    if (og == 0) {
        float af[8], ag[8];
#pragma unroll
        for (int j = 0; j < 8; j += 2) {
            const float* w0 = Wq + j * 64;
            const float* w1 = w0 + 64;
            float a00 = 0.f, a01 = 0.f, a10 = 0.f, a11 = 0.f;
#pragma unroll
            for (int c = 0; c < 64; c += 2) {
                a00 += w0[c] * xv[c];     a01 += w0[c + 1] * xv[c + 1];
                a10 += w1[c] * xv[c];     a11 += w1[c + 1] * xv[c + 1];
            }
            af[j] = bq[j] + a00 + a01;
            af[j + 1] = bq[j + 1] + a10 + a11;
        }
#pragma unroll
        for (int j = 0; j < 8; j += 2) {
            const float* w0 = Wk + j * 64;
            const float* w1 = w0 + 64;
            float a00 = 0.f, a01 = 0.f, a10 = 0.f, a11 = 0.f;
#pragma unroll
            for (int c = 0; c < 64; c += 2) {
                a00 += w0[c] * xv[c];     a01 += w0[c + 1] * xv[c + 1];
                a10 += w1[c] * xv[c];     a11 += w1[c + 1] * xv[c + 1];
            }
            ag[j] = bk[j] + a00 + a01;
            ag[j + 1] = bk[j + 1] + a10 + a11;
        }
        // per-column shift (cancels in p/l; only keeps p in fp16 range)
        float gn2 = 0.f;
#pragma unroll
        for (int j = 0; j < 8; j++) gn2 += ag[j] * ag[j];
        const float M = (LOG2E * 4.6f) * __builtin_sqrtf(gn2) + 1.0f;

        // fTR: [b][kt 64][ml 16][q 2][16 halves = t4 0..3 x 4]
        const int t4 = lane >> 4, ml = lane & 15;
        half4_t flo = {(_Float16)(af[0] * LOG2E), (_Float16)(af[1] * LOG2E),
                       (_Float16)(af[2] * LOG2E), (_Float16)(af[3] * LOG2E)};
        half4_t fhi = {(_Float16)(af[4] * LOG2E), (_Float16)(af[5] * LOG2E),
                       (_Float16)(af[6] * LOG2E), (_Float16)(af[7] * LOG2E)};
        __half* fb = fTR + ((size_t)b << 15) + ((size_t)(kt * 16 + ml) * 2) * 16 + t4 * 4;
        *(half4_t*)fb        = flo;   // q=0 slot
        *(half4_t*)(fb + 16) = fhi;   // q=1 slot

        half8_t glo, gpad;
#pragma unroll
        for (int j = 0; j < 8; j++) glo[j] = (_Float16)ag[j];
        gpad = (half8_t){};
        gpad[0] = (_Float16)(-M);
        __half* gp = gT16 + (size_t)((b << 12) + n) * 16;
        *(half8_t*)gp       = glo;
        *(half8_t*)(gp + 8) = gpad;
    } else {
        const int ch0 = (og - 1) * 16;
        float acc[16];
#pragma unroll
        for (int j = 0; j < 16; j += 2) {
            const float* w0 = Wv + (ch0 + j) * 64;
            const float* w1 = w0 + 64;
            float a00 = 0.f, a01 = 0.f, a10 = 0.f, a11 = 0.f;
#pragma unroll
            for (int c = 0; c < 64; c += 2) {
                a00 += w0[c] * xv[c];     a01 += w0[c + 1] * xv[c + 1];
                a10 += w1[c] * xv[c];     a11 += w1[c + 1] * xv[c + 1];
            }
            acc[j] = bv[ch0 + j] + a00 + a01;
            acc[j + 1] = bv[ch0 + j + 1] + a10 + a11;
        }
#pragma unroll
        for (int j = 0; j < 16; j++)
            hM[(((size_t)b * 64 + ch0 + j) << 12) + n] = __float2half(acc[j]);
    }
}

// ---------------- fused flash attention (key-split, shifted softmax) ---------
// grid (64 colblocks, 8 b, S), block 256 = 4 waves x 16 cols; NT = 64/S tiles.
template<int NT>
__global__ __launch_bounds__(256, 6) void attn_kernel(
    const __half* __restrict__ fTR, const __half* __restrict__ gT16,
    const __half* __restrict__ hM,
    __half* __restrict__ Pacc, float* __restrict__ Lsum)
{
    __shared__ __align__(16) _Float16 hl[2][64 * PRH];  // 2 x 9216 B
    const int tid   = threadIdx.x;
    const int w     = tid >> 6;
    const int lane  = tid & 63;
    const int q     = lane >> 4;
    const int ml    = lane & 15;
    const int b     = blockIdx.y;
    const int split = blockIdx.z;
    const int col   = blockIdx.x * 64 + w * 16 + ml;
    const bool qlo  = (q < 2);

    // g B-frag (K=16): pad halves carry {-M_col, 0, 0, 0} at q==2
    half4_t gfrag = *(const half4_t*)(gT16 + ((size_t)((b << 12) + col)) * 16 + q * 4);

    float4_t acc[4];
#pragma unroll
    for (int cg = 0; cg < 4; cg++) acc[cg] = (float4_t){0.f, 0.f, 0.f, 0.f};
    float ls0 = 0.f, ls1 = 0.f, ls2 = 0.f, ls3 = 0.f;

    const int kt0 = split * NT;
    const int c0  = tid >> 3;
    const int g0  = tid & 7;

    // rolling pointers
    const __half* srow0 = hM + ((size_t)(b * 64 + c0) << 12) + kt0 * 64 + g0 * 8;
    const __half* srow1 = srow0 + ((size_t)32 << 12);
    const __half* fptr  = fTR + ((size_t)b << 15) + (size_t)(kt0 * 16 + ml) * 32 + q * 16;

    // K-pad constants for f A-frag: q==2 supplies the "1" row, q==3 zeros
    half8_t padv = (half8_t){};
    if (q == 2) { padv[0] = (_Float16)1.0f; padv[4] = (_Float16)1.0f; }

    // ---- prologue: stage tile 0 + load its f record ----
    uint4 s0 = *(const uint4*)srow0;
    uint4 s1 = *(const uint4*)srow1;
    half8_t afn0 = padv, afn1 = padv;
    if (qlo) {
        afn0 = *(const half8_t*)fptr;
        afn1 = *(const half8_t*)(fptr + 8);
    }
    *(uint4*)(&hl[0][c0 * PRH + g0 * 8])        = s0;
    *(uint4*)(&hl[0][(c0 + 32) * PRH + g0 * 8]) = s1;
    __syncthreads();

    for (int kt = 0; kt < NT; kt++) {
        const _Float16* hbL = &hl[kt & 1][ml * PRH + q * 4];

        // ---- QK: 4 MFMA K=16, scores pre-shifted (log2 units) ----
        float4_t st0 = __builtin_amdgcn_mfma_f32_16x16x16f16(
            __builtin_shufflevector(afn0, afn0, 0, 1, 2, 3), gfrag,
            (float4_t){0.f, 0.f, 0.f, 0.f}, 0, 0, 0);
        float4_t st1 = __builtin_amdgcn_mfma_f32_16x16x16f16(
            __builtin_shufflevector(afn0, afn0, 4, 5, 6, 7), gfrag,
            (float4_t){0.f, 0.f, 0.f, 0.f}, 0, 0, 0);
        float4_t st2 = __builtin_amdgcn_mfma_f32_16x16x16f16(
            __builtin_shufflevector(afn1, afn1, 0, 1, 2, 3), gfrag,
            (float4_t){0.f, 0.f, 0.f, 0.f}, 0, 0, 0);
        float4_t st3 = __builtin_amdgcn_mfma_f32_16x16x16f16(
            __builtin_shufflevector(afn1, afn1, 4, 5, 6, 7), gfrag,
            (float4_t){0.f, 0.f, 0.f, 0.f}, 0, 0, 0);

        // ---- prefetch next tile (f record + h rows) ----
        if (kt + 1 < NT) {
            if (qlo) {
                afn0 = *(const half8_t*)(fptr + 512);
                afn1 = *(const half8_t*)(fptr + 520);
            }
            s0 = *(const uint4*)(srow0 + 64);
            s1 = *(const uint4*)(srow1 + 64);
            fptr  += 512;
            srow0 += 64;
            srow1 += 64;
        }

        // ---- softmax (fixed shift) + PV per 16-key group ----
        {
            float p0 = fexp2(st0[0]), p1 = fexp2(st0[1]),
                  p2 = fexp2(st0[2]), p3 = fexp2(st0[3]);
            ls0 += p0; ls1 += p1; ls2 += p2; ls3 += p3;
            half2_t plo = pkcvt(p0, p1), phi = pkcvt(p2, p3);
            half4_t pf = {plo[0], plo[1], phi[0], phi[1]};
#pragma unroll
            for (int cg = 0; cg < 4; cg++)
                acc[cg] = __builtin_amdgcn_mfma_f32_16x16x16f16(
                    *(const half4_t*)(hbL + cg * (16 * PRH) + 0 * 16), pf, acc[cg], 0, 0, 0);
        }
        {
            float p0 = fexp2(st1[0]), p1 = fexp2(st1[1]),
                  p2 = fexp2(st1[2]), p3 = fexp2(st1[3]);
            ls0 += p0; ls1 += p1; ls2 += p2; ls3 += p3;
            half2_t plo = pkcvt(p0, p1), phi = pkcvt(p2, p3);
            half4_t pf = {plo[0], plo[1], phi[0], phi[1]};
#pragma unroll
            for (int cg = 0; cg < 4; cg++)
                acc[cg] = __builtin_amdgcn_mfma_f32_16x16x16f16(
                    *(const half4_t*)(hbL + cg * (16 * PRH) + 1 * 16), pf, acc[cg], 0, 0, 0);
        }
        {
            float p0 = fexp2(st2[0]), p1 = fexp2(st2[1]),
                  p2 = fexp2(st2[2]), p3 = fexp2(st2[3]);
            ls0 += p0; ls1 += p1; ls2 += p2; ls3 += p3;
            half2_t plo = pkcvt(p0, p1), phi = pkcvt(p2, p3);
            half4_t pf = {plo[0], plo[1], phi[0], phi[1]};
#pragma unroll
            for (int cg = 0; cg < 4; cg++)
                acc[cg] = __builtin_amdgcn_mfma_f32_16x16x16f16(
                    *(const half4_t*)(hbL + cg * (16 * PRH) + 2 * 16), pf, acc[cg], 0, 0, 0);
        }
        {
            float p0 = fexp2(st3[0]), p1 = fexp2(st3[1]),
                  p2 = fexp2(st3[2]), p3 = fexp2(st3[3]);
            ls0 += p0; ls1 += p1; ls2 += p2; ls3 += p3;
            half2_t plo = pkcvt(p0, p1), phi = pkcvt(p2, p3);
            half4_t pf = {plo[0], plo[1], phi[0], phi[1]};
#pragma unroll
            for (int cg = 0; cg < 4; cg++)
                acc[cg] = __builtin_amdgcn_mfma_f32_16x16x16f16(
                    *(const half4_t*)(hbL + cg * (16 * PRH) + 3 * 16), pf, acc[cg], 0, 0, 0);
        }

        if (kt + 1 < NT) {
            _Float16* hn = &hl[(kt + 1) & 1][0];
            *(uint4*)(&hn[c0 * PRH + g0 * 8])        = s0;
            *(uint4*)(&hn[(c0 + 32) * PRH + g0 * 8]) = s1;
        }
        __syncthreads();
    }

    // ---- deferred l reduction over the column's 4 lanes ----
    float l = (ls0 + ls1) + (ls2 + ls3);
    l += __shfl_xor(l, 16, 64);
    l += __shfl_xor(l, 32, 64);

    // ---- store UNNORMALIZED partials (shift is split-invariant) ----
    __half* pa = Pacc + (((size_t)(split * 8 + b) * 64) << 12);
#pragma unroll
    for (int cg = 0; cg < 4; cg++)
#pragma unroll
        for (int r = 0; r < 4; r++) {
            int ch = cg * 16 + q * 4 + r;
            pa[((size_t)ch << 12) + col] = __float2half(acc[cg][r]);
        }
    if (q == 0)
        Lsum[((size_t)(split * 8 + b) << 12) + col] = l;
}

// ---------------- merge ------------------------------------------------------
// grid (64 col-tiles, 8 b, 4 ch-groups of 16), block 256 = 16 ch x 16 col-quads.
template<int S>
__global__ __launch_bounds__(256) void merge_kernel(
    const __half* __restrict__ Pacc, const float* __restrict__ Lsum,
    const float* __restrict__ x, const float* __restrict__ gammap,
    float* __restrict__ out)
{
    __shared__ float invL[64];
    const int tid  = threadIdx.x;
    const int c4   = tid & 15;
    const int chh  = tid >> 4;
    const int b    = blockIdx.y;
    const int col0 = blockIdx.x * 64;
    const int ch   = blockIdx.z * 16 + chh;

    if (tid < 64) {
        float L = 0.f;
#pragma unroll
        for (int s = 0; s < S; s++)
            L += Lsum[((size_t)(s * 8 + b) << 12) + col0 + tid];
        invL[tid] = gammap[0] / L;
    }
    __syncthreads();

    const int cc = c4 * 4;
    const size_t base = (((size_t)b * 64 + ch) << 12) + col0 + cc;
    float4 xv = *(const float4*)(x + base);
    float o0 = 0.f, o1 = 0.f, o2 = 0.f, o3 = 0.f;
#pragma unroll
    for (int s = 0; s < S; s++) {
        half4_t pv = *(const half4_t*)(Pacc +
            (((size_t)(s * 8 + b) * 64 + ch) << 12) + col0 + cc);
        o0 += (float)pv[0];
        o1 += (float)pv[1];
        o2 += (float)pv[2];
        o3 += (float)pv[3];
    }
    float4 ov;
    ov.x = o0 * invL[cc]     + xv.x;
    ov.y = o1 * invL[cc + 1] + xv.y;
    ov.z = o2 * invL[cc + 2] + xv.z;
    ov.w = o3 * invL[cc + 3] + xv.w;
    *(float4*)(out + base) = ov;
}

extern "C" void kernel_launch(void* const* d_in, const int* in_sizes, int n_in,
                              void* d_out, int out_size, void* d_ws, size_t ws_size,
                              hipStream_t stream) {
    const float* x     = (const float*)d_in[0];
    const float* Wq    = (const float*)d_in[1];
    const float* bq    = (const float*)d_in[2];
    const float* Wk    = (const float*)d_in[3];
    const float* bk    = (const float*)d_in[4];
    const float* Wv    = (const float*)d_in[5];
    const float* bv    = (const float*)d_in[6];
    const float* gamma = (const float*)d_in[7];
    float* out = (float*)d_out;

    const size_t fr_bytes  = (size_t)8 * 32768 * 2;             // 512 KB (fTR)
    const size_t g_bytes   = (size_t)8 * NTOK * 16 * 2;         // 1 MB
    const size_t hM_bytes  = (size_t)8 * 64 * NTOK * 2;         // 4 MB
    const size_t pa_split  = (size_t)8 * 64 * NTOK * 2;         // 4 MB per split
    const size_t l_split   = (size_t)8 * NTOK * sizeof(float);  // 128 KB per split
    const size_t base_need = fr_bytes + g_bytes + hM_bytes;

    int S = 1;
    if (ws_size >= base_need + 4 * (pa_split + l_split)) S = 4;
    else if (ws_size >= base_need + 2 * (pa_split + l_split)) S = 2;

    char* p = (char*)d_ws;
    __half* fTR  = (__half*)p;  p += fr_bytes;
    __half* gT16 = (__half*)p;  p += g_bytes;
    __half* hM   = (__half*)p;  p += hM_bytes;
    __half* Pacc = (__half*)p;  p += (size_t)S * pa_split;
    float*  Lsum = (float*)p;

    proj_kernel<<<dim3(64, 8, 5), 64, 0, stream>>>(x, Wq, bq, Wk, bk, Wv, bv,
                                                   fTR, gT16, hM);
    if (S == 4) {
        attn_kernel<16><<<dim3(64, 8, 4), 256, 0, stream>>>(fTR, gT16, hM, Pacc, Lsum);
        merge_kernel<4><<<dim3(64, 8, 4), 256, 0, stream>>>(Pacc, Lsum, x, gamma, out);
    } else if (S == 2) {
        attn_kernel<32><<<dim3(64, 8, 2), 256, 0, stream>>>(fTR, gT16, hM, Pacc, Lsum);
        merge_kernel<2><<<dim3(64, 8, 4), 256, 0, stream>>>(Pacc, Lsum, x, gamma, out);
    } else {
        attn_kernel<64><<<dim3(64, 8, 1), 256, 0, stream>>>(fTR, gT16, hM, Pacc, Lsum);
        merge_kernel<1><<<dim3(64, 8, 4), 256, 0, stream>>>(Pacc, Lsum, x, gamma, out);
    }
}

// Round 9
// 239.795 us; speedup vs baseline: 1.8256x; 1.8256x over previous
//
#include <hip/hip_runtime.h>
#include <hip/hip_fp16.h>

// SelfAttention: B=8, C=64, N=4096, d_head=8.
// o[b,c,m] = gamma * sum_n h[b,c,n] * softmax_n(f[:,n].g[:,m]) + x[b,c,m]
// R9 = R8 with attn __launch_bounds__(256,6) -> (256): the 6-waves/EU bound
// capped the unified VGPR+AGPR budget at ~85, starving arch VGPRs (40) and
// spilling the staging registers every K-tile (465 MB scratch writes).
// Packed f-frag records, consume-then-prefetch, unnormalized partials,
// invL merge, W-row proj.

typedef _Float16 half8_t __attribute__((ext_vector_type(8)));
typedef _Float16 half4_t __attribute__((ext_vector_type(4)));
typedef _Float16 half2_t __attribute__((ext_vector_type(2)));
typedef __fp16  fp16x2  __attribute__((ext_vector_type(2)));
typedef float float4_t __attribute__((ext_vector_type(4)));

#define NTOK 4096
#define PRH 72   // LDS h-row stride in halves (144 B: 16B-aligned, bank-rotating)
#define LOG2E 1.44269504088896340736f

#if __has_builtin(__builtin_amdgcn_exp2f)
__device__ __forceinline__ float fexp2(float x) { return __builtin_amdgcn_exp2f(x); }
#else
__device__ __forceinline__ float fexp2(float x) { return exp2f(x); }
#endif

__device__ __forceinline__ half2_t pkcvt(float a, float b) {
    fp16x2 v = __builtin_amdgcn_cvt_pkrtz(a, b);
    return __builtin_bit_cast(half2_t, v);
}

// ---------------- projection -------------------------------------------------
// grid (64 key-tiles, 8 b, 5 og), block = 1 wave (lane = column in tile).
// og 0: fTR packed frag records [b][kt*16+ml][q<2][t4][4] (log2e folded) +
//       gT16[col][16] = {g, -M_col, 0...}.  og 1..4: h channels (fp16 c-major).
__global__ __launch_bounds__(64, 4) void proj_kernel(
    const float* __restrict__ x,
    const float* __restrict__ Wq, const float* __restrict__ bq,
    const float* __restrict__ Wk, const float* __restrict__ bk,
    const float* __restrict__ Wv, const float* __restrict__ bv,
    __half* __restrict__ fTR, __half* __restrict__ gT16, __half* __restrict__ hM)
{
    const int lane = threadIdx.x;
    const int kt   = blockIdx.x;
    const int b    = blockIdx.y;
    const int og   = blockIdx.z;
    const int n    = kt * 64 + lane;

    float xv[64];
    const float* xb = x + (((size_t)b * 64) << 12) + n;
#pragma unroll
    for (int c = 0; c < 64; c++) xv[c] = xb[(size_t)c << 12];

    if (og == 0) {
        float af[8], ag[8];
#pragma unroll
        for (int j = 0; j < 8; j += 2) {
            const float* w0 = Wq + j * 64;
            const float* w1 = w0 + 64;
            float a00 = 0.f, a01 = 0.f, a10 = 0.f, a11 = 0.f;
#pragma unroll
            for (int c = 0; c < 64; c += 2) {
                a00 += w0[c] * xv[c];     a01 += w0[c + 1] * xv[c + 1];
                a10 += w1[c] * xv[c];     a11 += w1[c + 1] * xv[c + 1];
            }
            af[j] = bq[j] + a00 + a01;
            af[j + 1] = bq[j + 1] + a10 + a11;
        }
#pragma unroll
        for (int j = 0; j < 8; j += 2) {
            const float* w0 = Wk + j * 64;
            const float* w1 = w0 + 64;
            float a00 = 0.f, a01 = 0.f, a10 = 0.f, a11 = 0.f;
#pragma unroll
            for (int c = 0; c < 64; c += 2) {
                a00 += w0[c] * xv[c];     a01 += w0[c + 1] * xv[c + 1];
                a10 += w1[c] * xv[c];     a11 += w1[c + 1] * xv[c + 1];
            }
            ag[j] = bk[j] + a00 + a01;
            ag[j + 1] = bk[j + 1] + a10 + a11;
        }
        // per-column shift (cancels in p/l; only keeps p in fp16 range)
        float gn2 = 0.f;
#pragma unroll
        for (int j = 0; j < 8; j++) gn2 += ag[j] * ag[j];
        const float M = (LOG2E * 4.6f) * __builtin_sqrtf(gn2) + 1.0f;

        // fTR: [b][kt 64][ml 16][q 2][16 halves = t4 0..3 x 4]
        const int t4 = lane >> 4, ml = lane & 15;
        half4_t flo = {(_Float16)(af[0] * LOG2E), (_Float16)(af[1] * LOG2E),
                       (_Float16)(af[2] * LOG2E), (_Float16)(af[3] * LOG2E)};
        half4_t fhi = {(_Float16)(af[4] * LOG2E), (_Float16)(af[5] * LOG2E),
                       (_Float16)(af[6] * LOG2E), (_Float16)(af[7] * LOG2E)};
        __half* fb = fTR + ((size_t)b << 15) + ((size_t)(kt * 16 + ml) * 2) * 16 + t4 * 4;
        *(half4_t*)fb        = flo;   // q=0 slot
        *(half4_t*)(fb + 16) = fhi;   // q=1 slot

        half8_t glo, gpad;
#pragma unroll
        for (int j = 0; j < 8; j++) glo[j] = (_Float16)ag[j];
        gpad = (half8_t){};
        gpad[0] = (_Float16)(-M);
        __half* gp = gT16 + (size_t)((b << 12) + n) * 16;
        *(half8_t*)gp       = glo;
        *(half8_t*)(gp + 8) = gpad;
    } else {
        const int ch0 = (og - 1) * 16;
        float acc[16];
#pragma unroll
        for (int j = 0; j < 16; j += 2) {
            const float* w0 = Wv + (ch0 + j) * 64;
            const float* w1 = w0 + 64;
            float a00 = 0.f, a01 = 0.f, a10 = 0.f, a11 = 0.f;
#pragma unroll
            for (int c = 0; c < 64; c += 2) {
                a00 += w0[c] * xv[c];     a01 += w0[c + 1] * xv[c + 1];
                a10 += w1[c] * xv[c];     a11 += w1[c + 1] * xv[c + 1];
            }
            acc[j] = bv[ch0 + j] + a00 + a01;
            acc[j + 1] = bv[ch0 + j + 1] + a10 + a11;
        }
#pragma unroll
        for (int j = 0; j < 16; j++)
            hM[(((size_t)b * 64 + ch0 + j) << 12) + n] = __float2half(acc[j]);
    }
}

// ---------------- fused flash attention (key-split, shifted softmax) ---------
// grid (64 colblocks, 8 b, S), block 256 = 4 waves x 16 cols; NT = 64/S tiles.
template<int NT>
__global__ __launch_bounds__(256) void attn_kernel(
    const __half* __restrict__ fTR, const __half* __restrict__ gT16,
    const __half* __restrict__ hM,
    __half* __restrict__ Pacc, float* __restrict__ Lsum)
{
    __shared__ __align__(16) _Float16 hl[2][64 * PRH];  // 2 x 9216 B
    const int tid   = threadIdx.x;
    const int w     = tid >> 6;
    const int lane  = tid & 63;
    const int q     = lane >> 4;
    const int ml    = lane & 15;
    const int b     = blockIdx.y;
    const int split = blockIdx.z;
    const int col   = blockIdx.x * 64 + w * 16 + ml;
    const bool qlo  = (q < 2);

    // g B-frag (K=16): pad halves carry {-M_col, 0, 0, 0} at q==2
    half4_t gfrag = *(const half4_t*)(gT16 + ((size_t)((b << 12) + col)) * 16 + q * 4);

    float4_t acc[4];
#pragma unroll
    for (int cg = 0; cg < 4; cg++) acc[cg] = (float4_t){0.f, 0.f, 0.f, 0.f};
    float ls0 = 0.f, ls1 = 0.f, ls2 = 0.f, ls3 = 0.f;

    const int kt0 = split * NT;
    const int c0  = tid >> 3;
    const int g0  = tid & 7;

    // rolling pointers
    const __half* srow0 = hM + ((size_t)(b * 64 + c0) << 12) + kt0 * 64 + g0 * 8;
    const __half* srow1 = srow0 + ((size_t)32 << 12);
    const __half* fptr  = fTR + ((size_t)b << 15) + (size_t)(kt0 * 16 + ml) * 32 + q * 16;

    // K-pad constants for f A-frag: q==2 supplies the "1" row, q==3 zeros
    half8_t padv = (half8_t){};
    if (q == 2) { padv[0] = (_Float16)1.0f; padv[4] = (_Float16)1.0f; }

    // ---- prologue: stage tile 0 + load its f record ----
    uint4 s0 = *(const uint4*)srow0;
    uint4 s1 = *(const uint4*)srow1;
    half8_t afn0 = padv, afn1 = padv;
    if (qlo) {
        afn0 = *(const half8_t*)fptr;
        afn1 = *(const half8_t*)(fptr + 8);
    }
    *(uint4*)(&hl[0][c0 * PRH + g0 * 8])        = s0;
    *(uint4*)(&hl[0][(c0 + 32) * PRH + g0 * 8]) = s1;
    __syncthreads();

    for (int kt = 0; kt < NT; kt++) {
        const _Float16* hbL = &hl[kt & 1][ml * PRH + q * 4];

        // ---- QK: 4 MFMA K=16, scores pre-shifted (log2 units) ----
        float4_t st0 = __builtin_amdgcn_mfma_f32_16x16x16f16(
            __builtin_shufflevector(afn0, afn0, 0, 1, 2, 3), gfrag,
            (float4_t){0.f, 0.f, 0.f, 0.f}, 0, 0, 0);
        float4_t st1 = __builtin_amdgcn_mfma_f32_16x16x16f16(
            __builtin_shufflevector(afn0, afn0, 4, 5, 6, 7), gfrag,
            (float4_t){0.f, 0.f, 0.f, 0.f}, 0, 0, 0);
        float4_t st2 = __builtin_amdgcn_mfma_f32_16x16x16f16(
            __builtin_shufflevector(afn1, afn1, 0, 1, 2, 3), gfrag,
            (float4_t){0.f, 0.f, 0.f, 0.f}, 0, 0, 0);
        float4_t st3 = __builtin_amdgcn_mfma_f32_16x16x16f16(
            __builtin_shufflevector(afn1, afn1, 4, 5, 6, 7), gfrag,
            (float4_t){0.f, 0.f, 0.f, 0.f}, 0, 0, 0);

        // ---- prefetch next tile (f record + h rows) ----
        if (kt + 1 < NT) {
            if (qlo) {
                afn0 = *(const half8_t*)(fptr + 512);
                afn1 = *(const half8_t*)(fptr + 520);
            }
            s0 = *(const uint4*)(srow0 + 64);
            s1 = *(const uint4*)(srow1 + 64);
            fptr  += 512;
            srow0 += 64;
            srow1 += 64;
        }

        // ---- softmax (fixed shift) + PV per 16-key group ----
        {
            float p0 = fexp2(st0[0]), p1 = fexp2(st0[1]),
                  p2 = fexp2(st0[2]), p3 = fexp2(st0[3]);
            ls0 += p0; ls1 += p1; ls2 += p2; ls3 += p3;
            half2_t plo = pkcvt(p0, p1), phi = pkcvt(p2, p3);
            half4_t pf = {plo[0], plo[1], phi[0], phi[1]};
#pragma unroll
            for (int cg = 0; cg < 4; cg++)
                acc[cg] = __builtin_amdgcn_mfma_f32_16x16x16f16(
                    *(const half4_t*)(hbL + cg * (16 * PRH) + 0 * 16), pf, acc[cg], 0, 0, 0);
        }
        {
            float p0 = fexp2(st1[0]), p1 = fexp2(st1[1]),
                  p2 = fexp2(st1[2]), p3 = fexp2(st1[3]);
            ls0 += p0; ls1 += p1; ls2 += p2; ls3 += p3;
            half2_t plo = pkcvt(p0, p1), phi = pkcvt(p2, p3);
            half4_t pf = {plo[0], plo[1], phi[0], phi[1]};
#pragma unroll
            for (int cg = 0; cg < 4; cg++)
                acc[cg] = __builtin_amdgcn_mfma_f32_16x16x16f16(
                    *(const half4_t*)(hbL + cg * (16 * PRH) + 1 * 16), pf, acc[cg], 0, 0, 0);
        }
        {
            float p0 = fexp2(st2[0]), p1 = fexp2(st2[1]),
                  p2 = fexp2(st2[2]), p3 = fexp2(st2[3]);
            ls0 += p0; ls1 += p1; ls2 += p2; ls3 += p3;
            half2_t plo = pkcvt(p0, p1), phi = pkcvt(p2, p3);
            half4_t pf = {plo[0], plo[1], phi[0], phi[1]};
#pragma unroll
            for (int cg = 0; cg < 4; cg++)
                acc[cg] = __builtin_amdgcn_mfma_f32_16x16x16f16(
                    *(const half4_t*)(hbL + cg * (16 * PRH) + 2 * 16), pf, acc[cg], 0, 0, 0);
        }
        {
            float p0 = fexp2(st3[0]), p1 = fexp2(st3[1]),
                  p2 = fexp2(st3[2]), p3 = fexp2(st3[3]);
            ls0 += p0; ls1 += p1; ls2 += p2; ls3 += p3;
            half2_t plo = pkcvt(p0, p1), phi = pkcvt(p2, p3);
            half4_t pf = {plo[0], plo[1], phi[0], phi[1]};
#pragma unroll
            for (int cg = 0; cg < 4; cg++)
                acc[cg] = __builtin_amdgcn_mfma_f32_16x16x16f16(
                    *(const half4_t*)(hbL + cg * (16 * PRH) + 3 * 16), pf, acc[cg], 0, 0, 0);
        }

        if (kt + 1 < NT) {
            _Float16* hn = &hl[(kt + 1) & 1][0];
            *(uint4*)(&hn[c0 * PRH + g0 * 8])        = s0;
            *(uint4*)(&hn[(c0 + 32) * PRH + g0 * 8]) = s1;
        }
        __syncthreads();
    }

    // ---- deferred l reduction over the column's 4 lanes ----
    float l = (ls0 + ls1) + (ls2 + ls3);
    l += __shfl_xor(l, 16, 64);
    l += __shfl_xor(l, 32, 64);

    // ---- store UNNORMALIZED partials (shift is split-invariant) ----
    __half* pa = Pacc + (((size_t)(split * 8 + b) * 64) << 12);
#pragma unroll
    for (int cg = 0; cg < 4; cg++)
#pragma unroll
        for (int r = 0; r < 4; r++) {
            int ch = cg * 16 + q * 4 + r;
            pa[((size_t)ch << 12) + col] = __float2half(acc[cg][r]);
        }
    if (q == 0)
        Lsum[((size_t)(split * 8 + b) << 12) + col] = l;
}

// ---------------- merge ------------------------------------------------------
// grid (64 col-tiles, 8 b, 4 ch-groups of 16), block 256 = 16 ch x 16 col-quads.
template<int S>
__global__ __launch_bounds__(256) void merge_kernel(
    const __half* __restrict__ Pacc, const float* __restrict__ Lsum,
    const float* __restrict__ x, const float* __restrict__ gammap,
    float* __restrict__ out)
{
    __shared__ float invL[64];
    const int tid  = threadIdx.x;
    const int c4   = tid & 15;
    const int chh  = tid >> 4;
    const int b    = blockIdx.y;
    const int col0 = blockIdx.x * 64;
    const int ch   = blockIdx.z * 16 + chh;

    if (tid < 64) {
        float L = 0.f;
#pragma unroll
        for (int s = 0; s < S; s++)
            L += Lsum[((size_t)(s * 8 + b) << 12) + col0 + tid];
        invL[tid] = gammap[0] / L;
    }
    __syncthreads();

    const int cc = c4 * 4;
    const size_t base = (((size_t)b * 64 + ch) << 12) + col0 + cc;
    float4 xv = *(const float4*)(x + base);
    float o0 = 0.f, o1 = 0.f, o2 = 0.f, o3 = 0.f;
#pragma unroll
    for (int s = 0; s < S; s++) {
        half4_t pv = *(const half4_t*)(Pacc +
            (((size_t)(s * 8 + b) * 64 + ch) << 12) + col0 + cc);
        o0 += (float)pv[0];
        o1 += (float)pv[1];
        o2 += (float)pv[2];
        o3 += (float)pv[3];
    }
    float4 ov;
    ov.x = o0 * invL[cc]     + xv.x;
    ov.y = o1 * invL[cc + 1] + xv.y;
    ov.z = o2 * invL[cc + 2] + xv.z;
    ov.w = o3 * invL[cc + 3] + xv.w;
    *(float4*)(out + base) = ov;
}

extern "C" void kernel_launch(void* const* d_in, const int* in_sizes, int n_in,
                              void* d_out, int out_size, void* d_ws, size_t ws_size,
                              hipStream_t stream) {
    const float* x     = (const float*)d_in[0];
    const float* Wq    = (const float*)d_in[1];
    const float* bq    = (const float*)d_in[2];
    const float* Wk    = (const float*)d_in[3];
    const float* bk    = (const float*)d_in[4];
    const float* Wv    = (const float*)d_in[5];
    const float* bv    = (const float*)d_in[6];
    const float* gamma = (const float*)d_in[7];
    float* out = (float*)d_out;

    const size_t fr_bytes  = (size_t)8 * 32768 * 2;             // 512 KB (fTR)
    const size_t g_bytes   = (size_t)8 * NTOK * 16 * 2;         // 1 MB
    const size_t hM_bytes  = (size_t)8 * 64 * NTOK * 2;         // 4 MB
    const size_t pa_split  = (size_t)8 * 64 * NTOK * 2;         // 4 MB per split
    const size_t l_split   = (size_t)8 * NTOK * sizeof(float);  // 128 KB per split
    const size_t base_need = fr_bytes + g_bytes + hM_bytes;

    int S = 1;
    if (ws_size >= base_need + 4 * (pa_split + l_split)) S = 4;
    else if (ws_size >= base_need + 2 * (pa_split + l_split)) S = 2;

    char* p = (char*)d_ws;
    __half* fTR  = (__half*)p;  p += fr_bytes;
    __half* gT16 = (__half*)p;  p += g_bytes;
    __half* hM   = (__half*)p;  p += hM_bytes;
    __half* Pacc = (__half*)p;  p += (size_t)S * pa_split;
    float*  Lsum = (float*)p;

    proj_kernel<<<dim3(64, 8, 5), 64, 0, stream>>>(x, Wq, bq, Wk, bk, Wv, bv,
                                                   fTR, gT16, hM);
    if (S == 4) {
        attn_kernel<16><<<dim3(64, 8, 4), 256, 0, stream>>>(fTR, gT16, hM, Pacc, Lsum);
        merge_kernel<4><<<dim3(64, 8, 4), 256, 0, stream>>>(Pacc, Lsum, x, gamma, out);
    } else if (S == 2) {
        attn_kernel<32><<<dim3(64, 8, 2), 256, 0, stream>>>(fTR, gT16, hM, Pacc, Lsum);
        merge_kernel<2><<<dim3(64, 8, 4), 256, 0, stream>>>(Pacc, Lsum, x, gamma, out);
    } else {
        attn_kernel<64><<<dim3(64, 8, 1), 256, 0, stream>>>(fTR, gT16, hM, Pacc, Lsum);
        merge_kernel<1><<<dim3(64, 8, 4), 256, 0, stream>>>(Pacc, Lsum, x, gamma, out);
    }
}

// Round 10
// 137.822 us; speedup vs baseline: 3.1763x; 1.7399x over previous
//
#include <hip/hip_runtime.h>
#include <hip/hip_fp16.h>

// SelfAttention: B=8, C=64, N=4096, d_head=8.
// o[b,c,m] = gamma * sum_n h[b,c,n] * softmax_n(f[:,n].g[:,m]) + x[b,c,m]
// R10: proj rewritten with LDS-staged x tile + acc[16]-only per-lane state
// (R9's xv[64] spilled 67MB of scratch: VGPR budget 64 < 90 needed);
// attn kt-loop forced to unroll 1 (templated NT caused full unroll ->
// VGPR 160, occupancy 10%) and b64 frag loads without shufflevector.

typedef _Float16 half8_t __attribute__((ext_vector_type(8)));
typedef _Float16 half4_t __attribute__((ext_vector_type(4)));
typedef _Float16 half2_t __attribute__((ext_vector_type(2)));
typedef __fp16  fp16x2  __attribute__((ext_vector_type(2)));
typedef float float4_t __attribute__((ext_vector_type(4)));

#define NTOK 4096
#define PRH 72   // LDS h-row stride in halves (144 B: 16B-aligned, bank-rotating)
#define LOG2E 1.44269504088896340736f

#if __has_builtin(__builtin_amdgcn_exp2f)
__device__ __forceinline__ float fexp2(float x) { return __builtin_amdgcn_exp2f(x); }
#else
__device__ __forceinline__ float fexp2(float x) { return exp2f(x); }
#endif

__device__ __forceinline__ half2_t pkcvt(float a, float b) {
    fp16x2 v = __builtin_amdgcn_cvt_pkrtz(a, b);
    return __builtin_bit_cast(half2_t, v);
}

// ---------------- projection -------------------------------------------------
// grid (64 n-tiles, 8 b), block 320 = 5 waves. x tile staged in LDS.
// wave 0: f(8)+g(8) -> fTR records + gT16; waves 1-4: h channels (w-1)*16..+15.
// Per-lane state: acc[16] only (~28 VGPR) -> no spill regardless of budget.
__global__ __launch_bounds__(320) void proj_kernel(
    const float* __restrict__ x,
    const float* __restrict__ Wq, const float* __restrict__ bq,
    const float* __restrict__ Wk, const float* __restrict__ bk,
    const float* __restrict__ Wv, const float* __restrict__ bv,
    __half* __restrict__ fTR, __half* __restrict__ gT16, __half* __restrict__ hM)
{
    __shared__ float xl[64 * 64];   // 16 KB
    const int t  = threadIdx.x;
    const int kt = blockIdx.x;
    const int b  = blockIdx.y;
    const int n0 = kt * 64;

    // stage x[b][0..63][n0..n0+63] (each row = 256 B, float4-coalesced)
    if (t < 256) {
        const int f4 = t & 15;
        const int cb = t >> 4;
#pragma unroll
        for (int i = 0; i < 4; i++) {
            const int c = cb + i * 16;
            float4 v = *(const float4*)(x + (((size_t)(b * 64 + c)) << 12) + n0 + f4 * 4);
            *(float4*)(&xl[c * 64 + f4 * 4]) = v;
        }
    }
    __syncthreads();

    const int w    = t >> 6;
    const int lane = t & 63;
    const int n    = n0 + lane;
    float acc[16];

    if (w == 0) {
        // acc[0..7] = f, acc[8..15] = g
#pragma unroll
        for (int j = 0; j < 8; j++) { acc[j] = bq[j]; acc[8 + j] = bk[j]; }
        for (int c = 0; c < 64; c++) {
            const float xc = xl[c * 64 + lane];
#pragma unroll
            for (int j = 0; j < 8; j++) {
                acc[j]     += Wq[j * 64 + c] * xc;
                acc[8 + j] += Wk[j * 64 + c] * xc;
            }
        }
        // per-column shift (cancels in p/l; keeps p in fp16 range)
        float gn2 = 0.f;
#pragma unroll
        for (int j = 0; j < 8; j++) gn2 += acc[8 + j] * acc[8 + j];
        const float M = (LOG2E * 4.6f) * __builtin_sqrtf(gn2) + 1.0f;

        // fTR record: [b][kt*16+ml][q slot 16 halves][t4*4..]
        const int t4 = lane >> 4, ml = lane & 15;
        half4_t flo = {(_Float16)(acc[0] * LOG2E), (_Float16)(acc[1] * LOG2E),
                       (_Float16)(acc[2] * LOG2E), (_Float16)(acc[3] * LOG2E)};
        half4_t fhi = {(_Float16)(acc[4] * LOG2E), (_Float16)(acc[5] * LOG2E),
                       (_Float16)(acc[6] * LOG2E), (_Float16)(acc[7] * LOG2E)};
        __half* fb = fTR + ((size_t)b << 15) + (size_t)(kt * 16 + ml) * 32 + t4 * 4;
        *(half4_t*)fb        = flo;   // q=0 slot
        *(half4_t*)(fb + 16) = fhi;   // q=1 slot

        half8_t glo, gpad;
#pragma unroll
        for (int j = 0; j < 8; j++) glo[j] = (_Float16)acc[8 + j];
        gpad = (half8_t){};
        gpad[0] = (_Float16)(-M);
        __half* gp = gT16 + (size_t)((b << 12) + n) * 16;
        *(half8_t*)gp       = glo;
        *(half8_t*)(gp + 8) = gpad;
    } else {
        const int ch0 = (w - 1) * 16;
#pragma unroll
        for (int j = 0; j < 16; j++) acc[j] = bv[ch0 + j];
        for (int c = 0; c < 64; c++) {
            const float xc = xl[c * 64 + lane];
#pragma unroll
            for (int j = 0; j < 16; j++) acc[j] += Wv[(ch0 + j) * 64 + c] * xc;
        }
#pragma unroll
        for (int j = 0; j < 16; j++)
            hM[(((size_t)b * 64 + ch0 + j) << 12) + n] = __float2half(acc[j]);
    }
}

// ---------------- fused flash attention (key-split, shifted softmax) ---------
// grid (64 colblocks, 8 b, S), block 256 = 4 waves x 16 cols; NT = 64/S tiles.
template<int NT>
__global__ __launch_bounds__(256) void attn_kernel(
    const __half* __restrict__ fTR, const __half* __restrict__ gT16,
    const __half* __restrict__ hM,
    __half* __restrict__ Pacc, float* __restrict__ Lsum)
{
    __shared__ __align__(16) _Float16 hl[2][64 * PRH];  // 2 x 9216 B
    const int tid   = threadIdx.x;
    const int w     = tid >> 6;
    const int lane  = tid & 63;
    const int q     = lane >> 4;
    const int ml    = lane & 15;
    const int b     = blockIdx.y;
    const int split = blockIdx.z;
    const int col   = blockIdx.x * 64 + w * 16 + ml;
    const bool qlo  = (q < 2);

    // g B-frag (K=16): pad halves carry {-M_col, 0, 0, 0} at q==2
    half4_t gfrag = *(const half4_t*)(gT16 + ((size_t)((b << 12) + col)) * 16 + q * 4);

    float4_t acc[4];
#pragma unroll
    for (int cg = 0; cg < 4; cg++) acc[cg] = (float4_t){0.f, 0.f, 0.f, 0.f};
    float ls0 = 0.f, ls1 = 0.f, ls2 = 0.f, ls3 = 0.f;

    const int kt0 = split * NT;
    const int c0  = tid >> 3;
    const int g0  = tid & 7;

    // rolling pointers
    const __half* srow0 = hM + ((size_t)(b * 64 + c0) << 12) + kt0 * 64 + g0 * 8;
    const __half* srow1 = srow0 + ((size_t)32 << 12);
    const __half* fptr  = fTR + ((size_t)b << 15) + (size_t)(kt0 * 16 + ml) * 32 + q * 16;

    // K-pad constants for f A-frag: q==2 supplies the "1" row, q==3 zeros
    half4_t padv = (half4_t){};
    if (q == 2) padv[0] = (_Float16)1.0f;

    // ---- prologue: stage tile 0 + load its f record (4 x b64) ----
    uint4 s0 = *(const uint4*)srow0;
    uint4 s1 = *(const uint4*)srow1;
    half4_t afn0 = padv, afn1 = padv, afn2 = padv, afn3 = padv;
    if (qlo) {
        afn0 = *(const half4_t*)(fptr);
        afn1 = *(const half4_t*)(fptr + 4);
        afn2 = *(const half4_t*)(fptr + 8);
        afn3 = *(const half4_t*)(fptr + 12);
    }
    *(uint4*)(&hl[0][c0 * PRH + g0 * 8])        = s0;
    *(uint4*)(&hl[0][(c0 + 32) * PRH + g0 * 8]) = s1;
    __syncthreads();

#pragma unroll 1
    for (int kt = 0; kt < NT; kt++) {
        const _Float16* hbL = &hl[kt & 1][ml * PRH + q * 4];

        // ---- QK: 4 MFMA K=16, scores pre-shifted (log2 units) ----
        float4_t st0 = __builtin_amdgcn_mfma_f32_16x16x16f16(
            afn0, gfrag, (float4_t){0.f, 0.f, 0.f, 0.f}, 0, 0, 0);
        float4_t st1 = __builtin_amdgcn_mfma_f32_16x16x16f16(
            afn1, gfrag, (float4_t){0.f, 0.f, 0.f, 0.f}, 0, 0, 0);
        float4_t st2 = __builtin_amdgcn_mfma_f32_16x16x16f16(
            afn2, gfrag, (float4_t){0.f, 0.f, 0.f, 0.f}, 0, 0, 0);
        float4_t st3 = __builtin_amdgcn_mfma_f32_16x16x16f16(
            afn3, gfrag, (float4_t){0.f, 0.f, 0.f, 0.f}, 0, 0, 0);

        // ---- prefetch next tile (f record + h rows) ----
        if (kt + 1 < NT) {
            if (qlo) {
                afn0 = *(const half4_t*)(fptr + 512);
                afn1 = *(const half4_t*)(fptr + 516);
                afn2 = *(const half4_t*)(fptr + 520);
                afn3 = *(const half4_t*)(fptr + 524);
            }
            s0 = *(const uint4*)(srow0 + 64);
            s1 = *(const uint4*)(srow1 + 64);
            fptr  += 512;
            srow0 += 64;
            srow1 += 64;
        }

        // ---- softmax (fixed shift) + PV per 16-key group ----
        {
            float p0 = fexp2(st0[0]), p1 = fexp2(st0[1]),
                  p2 = fexp2(st0[2]), p3 = fexp2(st0[3]);
            ls0 += p0; ls1 += p1; ls2 += p2; ls3 += p3;
            half2_t plo = pkcvt(p0, p1), phi = pkcvt(p2, p3);
            half4_t pf = {plo[0], plo[1], phi[0], phi[1]};
#pragma unroll
            for (int cg = 0; cg < 4; cg++)
                acc[cg] = __builtin_amdgcn_mfma_f32_16x16x16f16(
                    *(const half4_t*)(hbL + cg * (16 * PRH) + 0 * 16), pf, acc[cg], 0, 0, 0);
        }
        {
            float p0 = fexp2(st1[0]), p1 = fexp2(st1[1]),
                  p2 = fexp2(st1[2]), p3 = fexp2(st1[3]);
            ls0 += p0; ls1 += p1; ls2 += p2; ls3 += p3;
            half2_t plo = pkcvt(p0, p1), phi = pkcvt(p2, p3);
            half4_t pf = {plo[0], plo[1], phi[0], phi[1]};
#pragma unroll
            for (int cg = 0; cg < 4; cg++)
                acc[cg] = __builtin_amdgcn_mfma_f32_16x16x16f16(
                    *(const half4_t*)(hbL + cg * (16 * PRH) + 1 * 16), pf, acc[cg], 0, 0, 0);
        }
        {
            float p0 = fexp2(st2[0]), p1 = fexp2(st2[1]),
                  p2 = fexp2(st2[2]), p3 = fexp2(st2[3]);
            ls0 += p0; ls1 += p1; ls2 += p2; ls3 += p3;
            half2_t plo = pkcvt(p0, p1), phi = pkcvt(p2, p3);
            half4_t pf = {plo[0], plo[1], phi[0], phi[1]};
#pragma unroll
            for (int cg = 0; cg < 4; cg++)
                acc[cg] = __builtin_amdgcn_mfma_f32_16x16x16f16(
                    *(const half4_t*)(hbL + cg * (16 * PRH) + 2 * 16), pf, acc[cg], 0, 0, 0);
        }
        {
            float p0 = fexp2(st3[0]), p1 = fexp2(st3[1]),
                  p2 = fexp2(st3[2]), p3 = fexp2(st3[3]);
            ls0 += p0; ls1 += p1; ls2 += p2; ls3 += p3;
            half2_t plo = pkcvt(p0, p1), phi = pkcvt(p2, p3);
            half4_t pf = {plo[0], plo[1], phi[0], phi[1]};
#pragma unroll
            for (int cg = 0; cg < 4; cg++)
                acc[cg] = __builtin_amdgcn_mfma_f32_16x16x16f16(
                    *(const half4_t*)(hbL + cg * (16 * PRH) + 3 * 16), pf, acc[cg], 0, 0, 0);
        }

        if (kt + 1 < NT) {
            _Float16* hn = &hl[(kt + 1) & 1][0];
            *(uint4*)(&hn[c0 * PRH + g0 * 8])        = s0;
            *(uint4*)(&hn[(c0 + 32) * PRH + g0 * 8]) = s1;
        }
        __syncthreads();
    }

    // ---- deferred l reduction over the column's 4 lanes ----
    float l = (ls0 + ls1) + (ls2 + ls3);
    l += __shfl_xor(l, 16, 64);
    l += __shfl_xor(l, 32, 64);

    // ---- store UNNORMALIZED partials (shift is split-invariant) ----
    __half* pa = Pacc + (((size_t)(split * 8 + b) * 64) << 12);
#pragma unroll
    for (int cg = 0; cg < 4; cg++)
#pragma unroll
        for (int r = 0; r < 4; r++) {
            int ch = cg * 16 + q * 4 + r;
            pa[((size_t)ch << 12) + col] = __float2half(acc[cg][r]);
        }
    if (q == 0)
        Lsum[((size_t)(split * 8 + b) << 12) + col] = l;
}

// ---------------- merge ------------------------------------------------------
// grid (64 col-tiles, 8 b, 4 ch-groups of 16), block 256 = 16 ch x 16 col-quads.
template<int S>
__global__ __launch_bounds__(256) void merge_kernel(
    const __half* __restrict__ Pacc, const float* __restrict__ Lsum,
    const float* __restrict__ x, const float* __restrict__ gammap,
    float* __restrict__ out)
{
    __shared__ float invL[64];
    const int tid  = threadIdx.x;
    const int c4   = tid & 15;
    const int chh  = tid >> 4;
    const int b    = blockIdx.y;
    const int col0 = blockIdx.x * 64;
    const int ch   = blockIdx.z * 16 + chh;

    if (tid < 64) {
        float L = 0.f;
#pragma unroll
        for (int s = 0; s < S; s++)
            L += Lsum[((size_t)(s * 8 + b) << 12) + col0 + tid];
        invL[tid] = gammap[0] / L;
    }
    __syncthreads();

    const int cc = c4 * 4;
    const size_t base = (((size_t)b * 64 + ch) << 12) + col0 + cc;
    float4 xv = *(const float4*)(x + base);
    float o0 = 0.f, o1 = 0.f, o2 = 0.f, o3 = 0.f;
#pragma unroll
    for (int s = 0; s < S; s++) {
        half4_t pv = *(const half4_t*)(Pacc +
            (((size_t)(s * 8 + b) * 64 + ch) << 12) + col0 + cc);
        o0 += (float)pv[0];
        o1 += (float)pv[1];
        o2 += (float)pv[2];
        o3 += (float)pv[3];
    }
    float4 ov;
    ov.x = o0 * invL[cc]     + xv.x;
    ov.y = o1 * invL[cc + 1] + xv.y;
    ov.z = o2 * invL[cc + 2] + xv.z;
    ov.w = o3 * invL[cc + 3] + xv.w;
    *(float4*)(out + base) = ov;
}

extern "C" void kernel_launch(void* const* d_in, const int* in_sizes, int n_in,
                              void* d_out, int out_size, void* d_ws, size_t ws_size,
                              hipStream_t stream) {
    const float* x     = (const float*)d_in[0];
    const float* Wq    = (const float*)d_in[1];
    const float* bq    = (const float*)d_in[2];
    const float* Wk    = (const float*)d_in[3];
    const float* bk    = (const float*)d_in[4];
    const float* Wv    = (const float*)d_in[5];
    const float* bv    = (const float*)d_in[6];
    const float* gamma = (const float*)d_in[7];
    float* out = (float*)d_out;

    const size_t fr_bytes  = (size_t)8 * 32768 * 2;             // 512 KB (fTR)
    const size_t g_bytes   = (size_t)8 * NTOK * 16 * 2;         // 1 MB
    const size_t hM_bytes  = (size_t)8 * 64 * NTOK * 2;         // 4 MB
    const size_t pa_split  = (size_t)8 * 64 * NTOK * 2;         // 4 MB per split
    const size_t l_split   = (size_t)8 * NTOK * sizeof(float);  // 128 KB per split
    const size_t base_need = fr_bytes + g_bytes + hM_bytes;

    int S = 1;
    if (ws_size >= base_need + 4 * (pa_split + l_split)) S = 4;
    else if (ws_size >= base_need + 2 * (pa_split + l_split)) S = 2;

    char* p = (char*)d_ws;
    __half* fTR  = (__half*)p;  p += fr_bytes;
    __half* gT16 = (__half*)p;  p += g_bytes;
    __half* hM   = (__half*)p;  p += hM_bytes;
    __half* Pacc = (__half*)p;  p += (size_t)S * pa_split;
    float*  Lsum = (float*)p;

    proj_kernel<<<dim3(64, 8), 320, 0, stream>>>(x, Wq, bq, Wk, bk, Wv, bv,
                                                 fTR, gT16, hM);
    if (S == 4) {
        attn_kernel<16><<<dim3(64, 8, 4), 256, 0, stream>>>(fTR, gT16, hM, Pacc, Lsum);
        merge_kernel<4><<<dim3(64, 8, 4), 256, 0, stream>>>(Pacc, Lsum, x, gamma, out);
    } else if (S == 2) {
        attn_kernel<32><<<dim3(64, 8, 2), 256, 0, stream>>>(fTR, gT16, hM, Pacc, Lsum);
        merge_kernel<2><<<dim3(64, 8, 4), 256, 0, stream>>>(Pacc, Lsum, x, gamma, out);
    } else {
        attn_kernel<64><<<dim3(64, 8, 1), 256, 0, stream>>>(fTR, gT16, hM, Pacc, Lsum);
        merge_kernel<1><<<dim3(64, 8, 4), 256, 0, stream>>>(Pacc, Lsum, x, gamma, out);
    }
}

// Round 11
// 136.263 us; speedup vs baseline: 3.2126x; 1.0114x over previous
//
#include <hip/hip_runtime.h>
#include <hip/hip_fp16.h>

// SelfAttention: B=8, C=64, N=4096, d_head=8.
// o[b,c,m] = gamma * sum_n h[b,c,n] * softmax_n(f[:,n].g[:,m]) + x[b,c,m]
// R11: attn 128-col blocks (32 cols/wave, 2 col-groups share every LDS h-read,
// f-load and staged tile -> LDS-pipe cost per column halves); merge rewritten
// to 128 B/thread with 16-B Pacc loads; proj xc software prefetch.

typedef _Float16 half8_t __attribute__((ext_vector_type(8)));
typedef _Float16 half4_t __attribute__((ext_vector_type(4)));
typedef _Float16 half2_t __attribute__((ext_vector_type(2)));
typedef __fp16  fp16x2  __attribute__((ext_vector_type(2)));
typedef float float4_t __attribute__((ext_vector_type(4)));

#define NTOK 4096
#define PRH 72   // LDS h-row stride in halves (144 B: 16B-aligned, bank-rotating)
#define LOG2E 1.44269504088896340736f

#if __has_builtin(__builtin_amdgcn_exp2f)
__device__ __forceinline__ float fexp2(float x) { return __builtin_amdgcn_exp2f(x); }
#else
__device__ __forceinline__ float fexp2(float x) { return exp2f(x); }
#endif

__device__ __forceinline__ half2_t pkcvt(float a, float b) {
    fp16x2 v = __builtin_amdgcn_cvt_pkrtz(a, b);
    return __builtin_bit_cast(half2_t, v);
}

// ---------------- projection -------------------------------------------------
// grid (64 n-tiles, 8 b), block 320 = 5 waves. x tile staged in LDS.
// wave 0: f(8)+g(8) -> fTR records + gT16; waves 1-4: h channels (w-1)*16..+15.
__global__ __launch_bounds__(320) void proj_kernel(
    const float* __restrict__ x,
    const float* __restrict__ Wq, const float* __restrict__ bq,
    const float* __restrict__ Wk, const float* __restrict__ bk,
    const float* __restrict__ Wv, const float* __restrict__ bv,
    __half* __restrict__ fTR, __half* __restrict__ gT16, __half* __restrict__ hM)
{
    __shared__ float xl[64 * 64];   // 16 KB
    const int t  = threadIdx.x;
    const int kt = blockIdx.x;
    const int b  = blockIdx.y;
    const int n0 = kt * 64;

    if (t < 256) {
        const int f4 = t & 15;
        const int cb = t >> 4;
#pragma unroll
        for (int i = 0; i < 4; i++) {
            const int c = cb + i * 16;
            float4 v = *(const float4*)(x + (((size_t)(b * 64 + c)) << 12) + n0 + f4 * 4);
            *(float4*)(&xl[c * 64 + f4 * 4]) = v;
        }
    }
    __syncthreads();

    const int w    = t >> 6;
    const int lane = t & 63;
    const int n    = n0 + lane;
    float acc[16];

    if (w == 0) {
#pragma unroll
        for (int j = 0; j < 8; j++) { acc[j] = bq[j]; acc[8 + j] = bk[j]; }
        float xc = xl[lane];
        for (int c = 0; c < 64; c++) {
            const float xn = (c < 63) ? xl[(c + 1) * 64 + lane] : 0.f;
#pragma unroll
            for (int j = 0; j < 8; j++) {
                acc[j]     += Wq[j * 64 + c] * xc;
                acc[8 + j] += Wk[j * 64 + c] * xc;
            }
            xc = xn;
        }
        float gn2 = 0.f;
#pragma unroll
        for (int j = 0; j < 8; j++) gn2 += acc[8 + j] * acc[8 + j];
        const float M = (LOG2E * 4.6f) * __builtin_sqrtf(gn2) + 1.0f;

        const int t4 = lane >> 4, ml = lane & 15;
        half4_t flo = {(_Float16)(acc[0] * LOG2E), (_Float16)(acc[1] * LOG2E),
                       (_Float16)(acc[2] * LOG2E), (_Float16)(acc[3] * LOG2E)};
        half4_t fhi = {(_Float16)(acc[4] * LOG2E), (_Float16)(acc[5] * LOG2E),
                       (_Float16)(acc[6] * LOG2E), (_Float16)(acc[7] * LOG2E)};
        __half* fb = fTR + ((size_t)b << 15) + (size_t)(kt * 16 + ml) * 32 + t4 * 4;
        *(half4_t*)fb        = flo;   // q=0 slot
        *(half4_t*)(fb + 16) = fhi;   // q=1 slot

        half8_t glo, gpad;
#pragma unroll
        for (int j = 0; j < 8; j++) glo[j] = (_Float16)acc[8 + j];
        gpad = (half8_t){};
        gpad[0] = (_Float16)(-M);
        __half* gp = gT16 + (size_t)((b << 12) + n) * 16;
        *(half8_t*)gp       = glo;
        *(half8_t*)(gp + 8) = gpad;
    } else {
        const int ch0 = (w - 1) * 16;
#pragma unroll
        for (int j = 0; j < 16; j++) acc[j] = bv[ch0 + j];
        float xc = xl[lane];
        for (int c = 0; c < 64; c++) {
            const float xn = (c < 63) ? xl[(c + 1) * 64 + lane] : 0.f;
#pragma unroll
            for (int j = 0; j < 16; j++) acc[j] += Wv[(ch0 + j) * 64 + c] * xc;
            xc = xn;
        }
#pragma unroll
        for (int j = 0; j < 16; j++)
            hM[(((size_t)b * 64 + ch0 + j) << 12) + n] = __float2half(acc[j]);
    }
}

// ---------------- fused flash attention (key-split, shifted softmax) ---------
// grid (32 colblocks of 128, 8 b, S), block 256 = 4 waves x 32 cols (2 groups).
// Both col-groups of a wave share every LDS h-read, f-load and staged tile.
template<int NT>
__global__ __launch_bounds__(256) void attn_kernel(
    const __half* __restrict__ fTR, const __half* __restrict__ gT16,
    const __half* __restrict__ hM,
    __half* __restrict__ Pacc, float* __restrict__ Lsum)
{
    __shared__ __align__(16) _Float16 hl[2][64 * PRH];  // 2 x 9216 B
    const int tid   = threadIdx.x;
    const int w     = tid >> 6;
    const int lane  = tid & 63;
    const int q     = lane >> 4;
    const int ml    = lane & 15;
    const int b     = blockIdx.y;
    const int split = blockIdx.z;
    const int colA  = blockIdx.x * 128 + w * 16 + ml;
    const int colB  = colA + 64;
    const bool qlo  = (q < 2);

    // g B-frags (K=16): pad halves carry {-M_col, 0, 0, 0} at q==2
    half4_t gfA = *(const half4_t*)(gT16 + ((size_t)((b << 12) + colA)) * 16 + q * 4);
    half4_t gfB = *(const half4_t*)(gT16 + ((size_t)((b << 12) + colB)) * 16 + q * 4);

    float4_t accA[4], accB[4];
#pragma unroll
    for (int cg = 0; cg < 4; cg++) {
        accA[cg] = (float4_t){0.f, 0.f, 0.f, 0.f};
        accB[cg] = (float4_t){0.f, 0.f, 0.f, 0.f};
    }
    float lsA0 = 0.f, lsA1 = 0.f, lsA2 = 0.f, lsA3 = 0.f;
    float lsB0 = 0.f, lsB1 = 0.f, lsB2 = 0.f, lsB3 = 0.f;

    const int kt0 = split * NT;
    const int c0  = tid >> 3;
    const int g0  = tid & 7;

    const __half* srow0 = hM + ((size_t)(b * 64 + c0) << 12) + kt0 * 64 + g0 * 8;
    const __half* srow1 = srow0 + ((size_t)32 << 12);
    const __half* fptr  = fTR + ((size_t)b << 15) + (size_t)(kt0 * 16 + ml) * 32 + q * 16;

    // K-pad: q==2 supplies the "1" row (pairs with g pad -M), q==3 zeros
    half4_t padv = (half4_t){};
    if (q == 2) padv[0] = (_Float16)1.0f;

    // ---- prologue ----
    uint4 s0 = *(const uint4*)srow0;
    uint4 s1 = *(const uint4*)srow1;
    half4_t afn0 = padv, afn1 = padv, afn2 = padv, afn3 = padv;
    if (qlo) {
        afn0 = *(const half4_t*)(fptr);
        afn1 = *(const half4_t*)(fptr + 4);
        afn2 = *(const half4_t*)(fptr + 8);
        afn3 = *(const half4_t*)(fptr + 12);
    }
    *(uint4*)(&hl[0][c0 * PRH + g0 * 8])        = s0;
    *(uint4*)(&hl[0][(c0 + 32) * PRH + g0 * 8]) = s1;
    __syncthreads();

#pragma unroll 1
    for (int kt = 0; kt < NT; kt++) {
        const _Float16* hbL = &hl[kt & 1][ml * PRH + q * 4];

        // ---- QK: 8 MFMA (4 t4-groups x 2 col-groups), shared afn ----
        float4_t stA0 = __builtin_amdgcn_mfma_f32_16x16x16f16(
            afn0, gfA, (float4_t){0.f, 0.f, 0.f, 0.f}, 0, 0, 0);
        float4_t stA1 = __builtin_amdgcn_mfma_f32_16x16x16f16(
            afn1, gfA, (float4_t){0.f, 0.f, 0.f, 0.f}, 0, 0, 0);
        float4_t stA2 = __builtin_amdgcn_mfma_f32_16x16x16f16(
            afn2, gfA, (float4_t){0.f, 0.f, 0.f, 0.f}, 0, 0, 0);
        float4_t stA3 = __builtin_amdgcn_mfma_f32_16x16x16f16(
            afn3, gfA, (float4_t){0.f, 0.f, 0.f, 0.f}, 0, 0, 0);
        float4_t stB0 = __builtin_amdgcn_mfma_f32_16x16x16f16(
            afn0, gfB, (float4_t){0.f, 0.f, 0.f, 0.f}, 0, 0, 0);
        float4_t stB1 = __builtin_amdgcn_mfma_f32_16x16x16f16(
            afn1, gfB, (float4_t){0.f, 0.f, 0.f, 0.f}, 0, 0, 0);
        float4_t stB2 = __builtin_amdgcn_mfma_f32_16x16x16f16(
            afn2, gfB, (float4_t){0.f, 0.f, 0.f, 0.f}, 0, 0, 0);
        float4_t stB3 = __builtin_amdgcn_mfma_f32_16x16x16f16(
            afn3, gfB, (float4_t){0.f, 0.f, 0.f, 0.f}, 0, 0, 0);

        // ---- prefetch next tile ----
        if (kt + 1 < NT) {
            if (qlo) {
                afn0 = *(const half4_t*)(fptr + 512);
                afn1 = *(const half4_t*)(fptr + 516);
                afn2 = *(const half4_t*)(fptr + 520);
                afn3 = *(const half4_t*)(fptr + 524);
            }
            s0 = *(const uint4*)(srow0 + 64);
            s1 = *(const uint4*)(srow1 + 64);
            fptr  += 512;
            srow0 += 64;
            srow1 += 64;
        }

        // ---- softmax + PV per 16-key group; ah shared by both col-groups ----
        {
            float pA0 = fexp2(stA0[0]), pA1 = fexp2(stA0[1]),
                  pA2 = fexp2(stA0[2]), pA3 = fexp2(stA0[3]);
            float pB0 = fexp2(stB0[0]), pB1 = fexp2(stB0[1]),
                  pB2 = fexp2(stB0[2]), pB3 = fexp2(stB0[3]);
            lsA0 += pA0; lsA1 += pA1; lsA2 += pA2; lsA3 += pA3;
            lsB0 += pB0; lsB1 += pB1; lsB2 += pB2; lsB3 += pB3;
            half2_t a_lo = pkcvt(pA0, pA1), a_hi = pkcvt(pA2, pA3);
            half2_t b_lo = pkcvt(pB0, pB1), b_hi = pkcvt(pB2, pB3);
            half4_t pfA = {a_lo[0], a_lo[1], a_hi[0], a_hi[1]};
            half4_t pfB = {b_lo[0], b_lo[1], b_hi[0], b_hi[1]};
#pragma unroll
            for (int cg = 0; cg < 4; cg++) {
                half4_t ah = *(const half4_t*)(hbL + cg * (16 * PRH) + 0 * 16);
                accA[cg] = __builtin_amdgcn_mfma_f32_16x16x16f16(ah, pfA, accA[cg], 0, 0, 0);
                accB[cg] = __builtin_amdgcn_mfma_f32_16x16x16f16(ah, pfB, accB[cg], 0, 0, 0);
            }
        }
        {
            float pA0 = fexp2(stA1[0]), pA1 = fexp2(stA1[1]),
                  pA2 = fexp2(stA1[2]), pA3 = fexp2(stA1[3]);
            float pB0 = fexp2(stB1[0]), pB1 = fexp2(stB1[1]),
                  pB2 = fexp2(stB1[2]), pB3 = fexp2(stB1[3]);
            lsA0 += pA0; lsA1 += pA1; lsA2 += pA2; lsA3 += pA3;
            lsB0 += pB0; lsB1 += pB1; lsB2 += pB2; lsB3 += pB3;
            half2_t a_lo = pkcvt(pA0, pA1), a_hi = pkcvt(pA2, pA3);
            half2_t b_lo = pkcvt(pB0, pB1), b_hi = pkcvt(pB2, pB3);
            half4_t pfA = {a_lo[0], a_lo[1], a_hi[0], a_hi[1]};
            half4_t pfB = {b_lo[0], b_lo[1], b_hi[0], b_hi[1]};
#pragma unroll
            for (int cg = 0; cg < 4; cg++) {
                half4_t ah = *(const half4_t*)(hbL + cg * (16 * PRH) + 1 * 16);
                accA[cg] = __builtin_amdgcn_mfma_f32_16x16x16f16(ah, pfA, accA[cg], 0, 0, 0);
                accB[cg] = __builtin_amdgcn_mfma_f32_16x16x16f16(ah, pfB, accB[cg], 0, 0, 0);
            }
        }
        {
            float pA0 = fexp2(stA2[0]), pA1 = fexp2(stA2[1]),
                  pA2 = fexp2(stA2[2]), pA3 = fexp2(stA2[3]);
            float pB0 = fexp2(stB2[0]), pB1 = fexp2(stB2[1]),
                  pB2 = fexp2(stB2[2]), pB3 = fexp2(stB2[3]);
            lsA0 += pA0; lsA1 += pA1; lsA2 += pA2; lsA3 += pA3;
            lsB0 += pB0; lsB1 += pB1; lsB2 += pB2; lsB3 += pB3;
            half2_t a_lo = pkcvt(pA0, pA1), a_hi = pkcvt(pA2, pA3);
            half2_t b_lo = pkcvt(pB0, pB1), b_hi = pkcvt(pB2, pB3);
            half4_t pfA = {a_lo[0], a_lo[1], a_hi[0], a_hi[1]};
            half4_t pfB = {b_lo[0], b_lo[1], b_hi[0], b_hi[1]};
#pragma unroll
            for (int cg = 0; cg < 4; cg++) {
                half4_t ah = *(const half4_t*)(hbL + cg * (16 * PRH) + 2 * 16);
                accA[cg] = __builtin_amdgcn_mfma_f32_16x16x16f16(ah, pfA, accA[cg], 0, 0, 0);
                accB[cg] = __builtin_amdgcn_mfma_f32_16x16x16f16(ah, pfB, accB[cg], 0, 0, 0);
            }
        }
        {
            float pA0 = fexp2(stA3[0]), pA1 = fexp2(stA3[1]),
                  pA2 = fexp2(stA3[2]), pA3 = fexp2(stA3[3]);
            float pB0 = fexp2(stB3[0]), pB1 = fexp2(stB3[1]),
                  pB2 = fexp2(stB3[2]), pB3 = fexp2(stB3[3]);
            lsA0 += pA0; lsA1 += pA1; lsA2 += pA2; lsA3 += pA3;
            lsB0 += pB0; lsB1 += pB1; lsB2 += pB2; lsB3 += pB3;
            half2_t a_lo = pkcvt(pA0, pA1), a_hi = pkcvt(pA2, pA3);
            half2_t b_lo = pkcvt(pB0, pB1), b_hi = pkcvt(pB2, pB3);
            half4_t pfA = {a_lo[0], a_lo[1], a_hi[0], a_hi[1]};
            half4_t pfB = {b_lo[0], b_lo[1], b_hi[0], b_hi[1]};
#pragma unroll
            for (int cg = 0; cg < 4; cg++) {
                half4_t ah = *(const half4_t*)(hbL + cg * (16 * PRH) + 3 * 16);
                accA[cg] = __builtin_amdgcn_mfma_f32_16x16x16f16(ah, pfA, accA[cg], 0, 0, 0);
                accB[cg] = __builtin_amdgcn_mfma_f32_16x16x16f16(ah, pfB, accB[cg], 0, 0, 0);
            }
        }

        if (kt + 1 < NT) {
            _Float16* hn = &hl[(kt + 1) & 1][0];
            *(uint4*)(&hn[c0 * PRH + g0 * 8])        = s0;
            *(uint4*)(&hn[(c0 + 32) * PRH + g0 * 8]) = s1;
        }
        __syncthreads();
    }

    // ---- deferred l reductions ----
    float lA = (lsA0 + lsA1) + (lsA2 + lsA3);
    lA += __shfl_xor(lA, 16, 64);
    lA += __shfl_xor(lA, 32, 64);
    float lB = (lsB0 + lsB1) + (lsB2 + lsB3);
    lB += __shfl_xor(lB, 16, 64);
    lB += __shfl_xor(lB, 32, 64);

    // ---- store UNNORMALIZED partials (shift is split-invariant) ----
    __half* pa = Pacc + (((size_t)(split * 8 + b) * 64) << 12);
#pragma unroll
    for (int cg = 0; cg < 4; cg++)
#pragma unroll
        for (int r = 0; r < 4; r++) {
            int ch = cg * 16 + q * 4 + r;
            pa[((size_t)ch << 12) + colA] = __float2half(accA[cg][r]);
            pa[((size_t)ch << 12) + colB] = __float2half(accB[cg][r]);
        }
    if (q == 0) {
        Lsum[((size_t)(split * 8 + b) << 12) + colA] = lA;
        Lsum[((size_t)(split * 8 + b) << 12) + colB] = lB;
    }
}

// ---------------- merge ------------------------------------------------------
// grid (64 col-tiles, 8 b, 2 ch-groups of 32), block 256 = 32 ch x 8 col-octs.
// 128 B/thread: half8 (16-B) Pacc loads, 8 cols x 1 ch per thread.
template<int S>
__global__ __launch_bounds__(256) void merge_kernel(
    const __half* __restrict__ Pacc, const float* __restrict__ Lsum,
    const float* __restrict__ x, const float* __restrict__ gammap,
    float* __restrict__ out)
{
    __shared__ float invL[64];
    const int tid  = threadIdx.x;
    const int oc   = tid & 7;
    const int chl  = tid >> 3;
    const int b    = blockIdx.y;
    const int col0 = blockIdx.x * 64;
    const int ch   = blockIdx.z * 32 + chl;

    if (tid < 64) {
        float L = 0.f;
#pragma unroll
        for (int s = 0; s < S; s++)
            L += Lsum[((size_t)(s * 8 + b) << 12) + col0 + tid];
        invL[tid] = gammap[0] / L;
    }
    __syncthreads();

    const int cc = oc * 8;
    const size_t base = (((size_t)b * 64 + ch) << 12) + col0 + cc;
    float o[8];
#pragma unroll
    for (int i = 0; i < 8; i++) o[i] = 0.f;
#pragma unroll
    for (int s = 0; s < S; s++) {
        half8_t pv = *(const half8_t*)(Pacc +
            (((size_t)(s * 8 + b) * 64 + ch) << 12) + col0 + cc);
#pragma unroll
        for (int i = 0; i < 8; i++) o[i] += (float)pv[i];
    }
    float4 x0 = *(const float4*)(x + base);
    float4 x1 = *(const float4*)(x + base + 4);
    float4 v0, v1;
    v0.x = o[0] * invL[cc]     + x0.x;
    v0.y = o[1] * invL[cc + 1] + x0.y;
    v0.z = o[2] * invL[cc + 2] + x0.z;
    v0.w = o[3] * invL[cc + 3] + x0.w;
    v1.x = o[4] * invL[cc + 4] + x1.x;
    v1.y = o[5] * invL[cc + 5] + x1.y;
    v1.z = o[6] * invL[cc + 6] + x1.z;
    v1.w = o[7] * invL[cc + 7] + x1.w;
    *(float4*)(out + base)     = v0;
    *(float4*)(out + base + 4) = v1;
}

extern "C" void kernel_launch(void* const* d_in, const int* in_sizes, int n_in,
                              void* d_out, int out_size, void* d_ws, size_t ws_size,
                              hipStream_t stream) {
    const float* x     = (const float*)d_in[0];
    const float* Wq    = (const float*)d_in[1];
    const float* bq    = (const float*)d_in[2];
    const float* Wk    = (const float*)d_in[3];
    const float* bk    = (const float*)d_in[4];
    const float* Wv    = (const float*)d_in[5];
    const float* bv    = (const float*)d_in[6];
    const float* gamma = (const float*)d_in[7];
    float* out = (float*)d_out;

    const size_t fr_bytes  = (size_t)8 * 32768 * 2;             // 512 KB (fTR)
    const size_t g_bytes   = (size_t)8 * NTOK * 16 * 2;         // 1 MB
    const size_t hM_bytes  = (size_t)8 * 64 * NTOK * 2;         // 4 MB
    const size_t pa_split  = (size_t)8 * 64 * NTOK * 2;         // 4 MB per split
    const size_t l_split   = (size_t)8 * NTOK * sizeof(float);  // 128 KB per split
    const size_t base_need = fr_bytes + g_bytes + hM_bytes;

    int S = 1;
    if (ws_size >= base_need + 4 * (pa_split + l_split)) S = 4;
    else if (ws_size >= base_need + 2 * (pa_split + l_split)) S = 2;

    char* p = (char*)d_ws;
    __half* fTR  = (__half*)p;  p += fr_bytes;
    __half* gT16 = (__half*)p;  p += g_bytes;
    __half* hM   = (__half*)p;  p += hM_bytes;
    __half* Pacc = (__half*)p;  p += (size_t)S * pa_split;
    float*  Lsum = (float*)p;

    proj_kernel<<<dim3(64, 8), 320, 0, stream>>>(x, Wq, bq, Wk, bk, Wv, bv,
                                                 fTR, gT16, hM);
    if (S == 4) {
        attn_kernel<16><<<dim3(32, 8, 4), 256, 0, stream>>>(fTR, gT16, hM, Pacc, Lsum);
        merge_kernel<4><<<dim3(64, 8, 2), 256, 0, stream>>>(Pacc, Lsum, x, gamma, out);
    } else if (S == 2) {
        attn_kernel<32><<<dim3(32, 8, 2), 256, 0, stream>>>(fTR, gT16, hM, Pacc, Lsum);
        merge_kernel<2><<<dim3(64, 8, 2), 256, 0, stream>>>(Pacc, Lsum, x, gamma, out);
    } else {
        attn_kernel<64><<<dim3(32, 8, 1), 256, 0, stream>>>(fTR, gT16, hM, Pacc, Lsum);
        merge_kernel<1><<<dim3(64, 8, 2), 256, 0, stream>>>(Pacc, Lsum, x, gamma, out);
    }
}

// Round 12
// 121.267 us; speedup vs baseline: 3.6099x; 1.1237x over previous
//
#include <hip/hip_runtime.h>
#include <hip/hip_fp16.h>

// SelfAttention: B=8, C=64, N=4096, d_head=8.
// o[b,c,m] = gamma * sum_n h[b,c,n] * softmax_n(f[:,n].g[:,m]) + x[b,c,m]
// R12: proj rewritten as MFMA GEMM (80x64x64-per-block). R9 accounting proved
// merge=4.4us and proj~83us: the W scalar-load + xc ds_read chain shares
// lgkmcnt -> latency-serialized. MFMA kills the W streaming path entirely.
// attn = R11 (128-col blocks, 2 col-groups/wave). merge = R10 form.

typedef _Float16 half8_t __attribute__((ext_vector_type(8)));
typedef _Float16 half4_t __attribute__((ext_vector_type(4)));
typedef _Float16 half2_t __attribute__((ext_vector_type(2)));
typedef __fp16  fp16x2  __attribute__((ext_vector_type(2)));
typedef float float4_t __attribute__((ext_vector_type(4)));

#define NTOK 4096
#define PRH 72   // LDS h-row stride in halves (144 B: 16B-aligned, bank-rotating)
#define LOG2E 1.44269504088896340736f

#if __has_builtin(__builtin_amdgcn_exp2f)
__device__ __forceinline__ float fexp2(float x) { return __builtin_amdgcn_exp2f(x); }
#else
__device__ __forceinline__ float fexp2(float x) { return exp2f(x); }
#endif

__device__ __forceinline__ half2_t pkcvt(float a, float b) {
    fp16x2 v = __builtin_amdgcn_cvt_pkrtz(a, b);
    return __builtin_bit_cast(half2_t, v);
}

// ---------------- projection (MFMA) ------------------------------------------
// grid (64 token-tiles, 8 b), block 320 = 5 waves = 5 out-row-groups of 16:
// wave0 rows = Wq(8)+Wk(8) stitched; waves1-4 = Wv rows (w-1)*16..+15.
// x tile staged TRANSPOSED to LDS fp16: xh[token][ch] (stride 72).
// Per wave: A-frags = W rows (4 float4 global loads/lane, once),
// B-frags = b64 LDS reads, 4 col-groups x 4 K-steps = 16 MFMA.
// D layout (col=token=lane&15, row=q*4+r) matches fTR/gT16/hM stores directly.
__global__ __launch_bounds__(320) void proj_kernel(
    const float* __restrict__ x,
    const float* __restrict__ Wq, const float* __restrict__ bq,
    const float* __restrict__ Wk, const float* __restrict__ bk,
    const float* __restrict__ Wv, const float* __restrict__ bv,
    __half* __restrict__ fTR, __half* __restrict__ gT16, __half* __restrict__ hM)
{
    __shared__ __align__(16) _Float16 xh[64 * PRH];   // [token][ch], 9216 B
    const int t  = threadIdx.x;
    const int kt = blockIdx.x;
    const int b  = blockIdx.y;
    const int n0 = kt * 64;

    // stage x[b][c][n0..+63] -> xh[tok][c] (fp16 transpose)
    if (t < 256) {
#pragma unroll
        for (int i = 0; i < 4; i++) {
            const int idx = t + i * 256;
            const int c = idx >> 4, f4 = idx & 15;
            float4 v = *(const float4*)(x + (((size_t)(b * 64 + c)) << 12) + n0 + f4 * 4);
            xh[(f4 * 4 + 0) * PRH + c] = (_Float16)v.x;
            xh[(f4 * 4 + 1) * PRH + c] = (_Float16)v.y;
            xh[(f4 * 4 + 2) * PRH + c] = (_Float16)v.z;
            xh[(f4 * 4 + 3) * PRH + c] = (_Float16)v.w;
        }
    }

    const int w    = t >> 6;
    const int lane = t & 63;
    const int q    = lane >> 4;
    const int ml   = lane & 15;

    // A-frags: W row (rg*16+ml), k = ks*16 + q*4 + j  (fp16 cvt once)
    const float* wrow;
    if (w == 0) wrow = (ml < 8) ? (Wq + ml * 64) : (Wk + (ml - 8) * 64);
    else        wrow = Wv + ((w - 1) * 16 + ml) * 64;
    half4_t afr[4];
#pragma unroll
    for (int ks = 0; ks < 4; ks++) {
        float4 wv4 = *(const float4*)(wrow + ks * 16 + q * 4);
        afr[ks] = (half4_t){(_Float16)wv4.x, (_Float16)wv4.y,
                            (_Float16)wv4.z, (_Float16)wv4.w};
    }
    // bias for rows q*4+r of this row-group
    float4 bias4;
    if (w == 0) bias4 = (q < 2) ? *(const float4*)(bq + q * 4)
                                : *(const float4*)(bk + (q - 2) * 4);
    else        bias4 = *(const float4*)(bv + (w - 1) * 16 + q * 4);

    __syncthreads();

#pragma unroll
    for (int cg = 0; cg < 4; cg++) {
        float4_t acc = (float4_t){0.f, 0.f, 0.f, 0.f};
#pragma unroll
        for (int ks = 0; ks < 4; ks++) {
            half4_t bfr = *(const half4_t*)(&xh[(cg * 16 + ml) * PRH + ks * 16 + q * 4]);
            acc = __builtin_amdgcn_mfma_f32_16x16x16f16(afr[ks], bfr, acc, 0, 0, 0);
        }
        acc[0] += bias4.x; acc[1] += bias4.y; acc[2] += bias4.z; acc[3] += bias4.w;
        const int tok = n0 + cg * 16 + ml;

        if (w == 0) {
            if (q < 2) {
                // f rows: fold log2e, one b64 to the packed frag record
                half4_t fv = {(_Float16)(acc[0] * LOG2E), (_Float16)(acc[1] * LOG2E),
                              (_Float16)(acc[2] * LOG2E), (_Float16)(acc[3] * LOG2E)};
                *(half4_t*)(fTR + ((size_t)b << 15) +
                            (size_t)(kt * 16 + ml) * 32 + q * 16 + cg * 4) = fv;
            }
            // g norm: rows 8-15 live in q=2 (g0..3) and q=3 (g4..7); xor16 pairs them
            float gn2p = acc[0] * acc[0] + acc[1] * acc[1] +
                         acc[2] * acc[2] + acc[3] * acc[3];
            float gn2 = gn2p + __shfl_xor(gn2p, 16, 64);
            if (q >= 2) {
                half4_t gv = {(_Float16)acc[0], (_Float16)acc[1],
                              (_Float16)acc[2], (_Float16)acc[3]};
                __half* gp = gT16 + (size_t)((b << 12) + tok) * 16;
                *(half4_t*)(gp + (q - 2) * 4) = gv;
                if (q == 2) {
                    const float M = (LOG2E * 4.6f) * __builtin_sqrtf(gn2) + 1.0f;
                    *(half4_t*)(gp + 8) = (half4_t){(_Float16)(-M), 0, 0, 0};
                } else {
                    *(half4_t*)(gp + 12) = (half4_t){};
                }
            }
        } else {
            const int ch = (w - 1) * 16 + q * 4;
#pragma unroll
            for (int r = 0; r < 4; r++)
                hM[(((size_t)b * 64 + ch + r) << 12) + tok] = __float2half(acc[r]);
        }
    }
}

// ---------------- fused flash attention (key-split, shifted softmax) ---------
// grid (32 colblocks of 128, 8 b, S), block 256 = 4 waves x 32 cols (2 groups).
template<int NT>
__global__ __launch_bounds__(256) void attn_kernel(
    const __half* __restrict__ fTR, const __half* __restrict__ gT16,
    const __half* __restrict__ hM,
    __half* __restrict__ Pacc, float* __restrict__ Lsum)
{
    __shared__ __align__(16) _Float16 hl[2][64 * PRH];  // 2 x 9216 B
    const int tid   = threadIdx.x;
    const int w     = tid >> 6;
    const int lane  = tid & 63;
    const int q     = lane >> 4;
    const int ml    = lane & 15;
    const int b     = blockIdx.y;
    const int split = blockIdx.z;
    const int colA  = blockIdx.x * 128 + w * 16 + ml;
    const int colB  = colA + 64;
    const bool qlo  = (q < 2);

    half4_t gfA = *(const half4_t*)(gT16 + ((size_t)((b << 12) + colA)) * 16 + q * 4);
    half4_t gfB = *(const half4_t*)(gT16 + ((size_t)((b << 12) + colB)) * 16 + q * 4);

    float4_t accA[4], accB[4];
#pragma unroll
    for (int cg = 0; cg < 4; cg++) {
        accA[cg] = (float4_t){0.f, 0.f, 0.f, 0.f};
        accB[cg] = (float4_t){0.f, 0.f, 0.f, 0.f};
    }
    float lsA0 = 0.f, lsA1 = 0.f, lsA2 = 0.f, lsA3 = 0.f;
    float lsB0 = 0.f, lsB1 = 0.f, lsB2 = 0.f, lsB3 = 0.f;

    const int kt0 = split * NT;
    const int c0  = tid >> 3;
    const int g0  = tid & 7;

    const __half* srow0 = hM + ((size_t)(b * 64 + c0) << 12) + kt0 * 64 + g0 * 8;
    const __half* srow1 = srow0 + ((size_t)32 << 12);
    const __half* fptr  = fTR + ((size_t)b << 15) + (size_t)(kt0 * 16 + ml) * 32 + q * 16;

    half4_t padv = (half4_t){};
    if (q == 2) padv[0] = (_Float16)1.0f;

    uint4 s0 = *(const uint4*)srow0;
    uint4 s1 = *(const uint4*)srow1;
    half4_t afn0 = padv, afn1 = padv, afn2 = padv, afn3 = padv;
    if (qlo) {
        afn0 = *(const half4_t*)(fptr);
        afn1 = *(const half4_t*)(fptr + 4);
        afn2 = *(const half4_t*)(fptr + 8);
        afn3 = *(const half4_t*)(fptr + 12);
    }
    *(uint4*)(&hl[0][c0 * PRH + g0 * 8])        = s0;
    *(uint4*)(&hl[0][(c0 + 32) * PRH + g0 * 8]) = s1;
    __syncthreads();

#pragma unroll 1
    for (int kt = 0; kt < NT; kt++) {
        const _Float16* hbL = &hl[kt & 1][ml * PRH + q * 4];

        float4_t stA0 = __builtin_amdgcn_mfma_f32_16x16x16f16(
            afn0, gfA, (float4_t){0.f, 0.f, 0.f, 0.f}, 0, 0, 0);
        float4_t stA1 = __builtin_amdgcn_mfma_f32_16x16x16f16(
            afn1, gfA, (float4_t){0.f, 0.f, 0.f, 0.f}, 0, 0, 0);
        float4_t stA2 = __builtin_amdgcn_mfma_f32_16x16x16f16(
            afn2, gfA, (float4_t){0.f, 0.f, 0.f, 0.f}, 0, 0, 0);
        float4_t stA3 = __builtin_amdgcn_mfma_f32_16x16x16f16(
            afn3, gfA, (float4_t){0.f, 0.f, 0.f, 0.f}, 0, 0, 0);
        float4_t stB0 = __builtin_amdgcn_mfma_f32_16x16x16f16(
            afn0, gfB, (float4_t){0.f, 0.f, 0.f, 0.f}, 0, 0, 0);
        float4_t stB1 = __builtin_amdgcn_mfma_f32_16x16x16f16(
            afn1, gfB, (float4_t){0.f, 0.f, 0.f, 0.f}, 0, 0, 0);
        float4_t stB2 = __builtin_amdgcn_mfma_f32_16x16x16f16(
            afn2, gfB, (float4_t){0.f, 0.f, 0.f, 0.f}, 0, 0, 0);
        float4_t stB3 = __builtin_amdgcn_mfma_f32_16x16x16f16(
            afn3, gfB, (float4_t){0.f, 0.f, 0.f, 0.f}, 0, 0, 0);

        if (kt + 1 < NT) {
            if (qlo) {
                afn0 = *(const half4_t*)(fptr + 512);
                afn1 = *(const half4_t*)(fptr + 516);
                afn2 = *(const half4_t*)(fptr + 520);
                afn3 = *(const half4_t*)(fptr + 524);
            }
            s0 = *(const uint4*)(srow0 + 64);
            s1 = *(const uint4*)(srow1 + 64);
            fptr  += 512;
            srow0 += 64;
            srow1 += 64;
        }

        {
            float pA0 = fexp2(stA0[0]), pA1 = fexp2(stA0[1]),
                  pA2 = fexp2(stA0[2]), pA3 = fexp2(stA0[3]);
            float pB0 = fexp2(stB0[0]), pB1 = fexp2(stB0[1]),
                  pB2 = fexp2(stB0[2]), pB3 = fexp2(stB0[3]);
            lsA0 += pA0; lsA1 += pA1; lsA2 += pA2; lsA3 += pA3;
            lsB0 += pB0; lsB1 += pB1; lsB2 += pB2; lsB3 += pB3;
            half2_t a_lo = pkcvt(pA0, pA1), a_hi = pkcvt(pA2, pA3);
            half2_t b_lo = pkcvt(pB0, pB1), b_hi = pkcvt(pB2, pB3);
            half4_t pfA = {a_lo[0], a_lo[1], a_hi[0], a_hi[1]};
            half4_t pfB = {b_lo[0], b_lo[1], b_hi[0], b_hi[1]};
#pragma unroll
            for (int cg = 0; cg < 4; cg++) {
                half4_t ah = *(const half4_t*)(hbL + cg * (16 * PRH) + 0 * 16);
                accA[cg] = __builtin_amdgcn_mfma_f32_16x16x16f16(ah, pfA, accA[cg], 0, 0, 0);
                accB[cg] = __builtin_amdgcn_mfma_f32_16x16x16f16(ah, pfB, accB[cg], 0, 0, 0);
            }
        }
        {
            float pA0 = fexp2(stA1[0]), pA1 = fexp2(stA1[1]),
                  pA2 = fexp2(stA1[2]), pA3 = fexp2(stA1[3]);
            float pB0 = fexp2(stB1[0]), pB1 = fexp2(stB1[1]),
                  pB2 = fexp2(stB1[2]), pB3 = fexp2(stB1[3]);
            lsA0 += pA0; lsA1 += pA1; lsA2 += pA2; lsA3 += pA3;
            lsB0 += pB0; lsB1 += pB1; lsB2 += pB2; lsB3 += pB3;
            half2_t a_lo = pkcvt(pA0, pA1), a_hi = pkcvt(pA2, pA3);
            half2_t b_lo = pkcvt(pB0, pB1), b_hi = pkcvt(pB2, pB3);
            half4_t pfA = {a_lo[0], a_lo[1], a_hi[0], a_hi[1]};
            half4_t pfB = {b_lo[0], b_lo[1], b_hi[0], b_hi[1]};
#pragma unroll
            for (int cg = 0; cg < 4; cg++) {
                half4_t ah = *(const half4_t*)(hbL + cg * (16 * PRH) + 1 * 16);
                accA[cg] = __builtin_amdgcn_mfma_f32_16x16x16f16(ah, pfA, accA[cg], 0, 0, 0);
                accB[cg] = __builtin_amdgcn_mfma_f32_16x16x16f16(ah, pfB, accB[cg], 0, 0, 0);
            }
        }
        {
            float pA0 = fexp2(stA2[0]), pA1 = fexp2(stA2[1]),
                  pA2 = fexp2(stA2[2]), pA3 = fexp2(stA2[3]);
            float pB0 = fexp2(stB2[0]), pB1 = fexp2(stB2[1]),
                  pB2 = fexp2(stB2[2]), pB3 = fexp2(stB2[3]);
            lsA0 += pA0; lsA1 += pA1; lsA2 += pA2; lsA3 += pA3;
            lsB0 += pB0; lsB1 += pB1; lsB2 += pB2; lsB3 += pB3;
            half2_t a_lo = pkcvt(pA0, pA1), a_hi = pkcvt(pA2, pA3);
            half2_t b_lo = pkcvt(pB0, pB1), b_hi = pkcvt(pB2, pB3);
            half4_t pfA = {a_lo[0], a_lo[1], a_hi[0], a_hi[1]};
            half4_t pfB = {b_lo[0], b_lo[1], b_hi[0], b_hi[1]};
#pragma unroll
            for (int cg = 0; cg < 4; cg++) {
                half4_t ah = *(const half4_t*)(hbL + cg * (16 * PRH) + 2 * 16);
                accA[cg] = __builtin_amdgcn_mfma_f32_16x16x16f16(ah, pfA, accA[cg], 0, 0, 0);
                accB[cg] = __builtin_amdgcn_mfma_f32_16x16x16f16(ah, pfB, accB[cg], 0, 0, 0);
            }
        }
        {
            float pA0 = fexp2(stA3[0]), pA1 = fexp2(stA3[1]),
                  pA2 = fexp2(stA3[2]), pA3 = fexp2(stA3[3]);
            float pB0 = fexp2(stB3[0]), pB1 = fexp2(stB3[1]),
                  pB2 = fexp2(stB3[2]), pB3 = fexp2(stB3[3]);
            lsA0 += pA0; lsA1 += pA1; lsA2 += pA2; lsA3 += pA3;
            lsB0 += pB0; lsB1 += pB1; lsB2 += pB2; lsB3 += pB3;
            half2_t a_lo = pkcvt(pA0, pA1), a_hi = pkcvt(pA2, pA3);
            half2_t b_lo = pkcvt(pB0, pB1), b_hi = pkcvt(pB2, pB3);
            half4_t pfA = {a_lo[0], a_lo[1], a_hi[0], a_hi[1]};
            half4_t pfB = {b_lo[0], b_lo[1], b_hi[0], b_hi[1]};
#pragma unroll
            for (int cg = 0; cg < 4; cg++) {
                half4_t ah = *(const half4_t*)(hbL + cg * (16 * PRH) + 3 * 16);
                accA[cg] = __builtin_amdgcn_mfma_f32_16x16x16f16(ah, pfA, accA[cg], 0, 0, 0);
                accB[cg] = __builtin_amdgcn_mfma_f32_16x16x16f16(ah, pfB, accB[cg], 0, 0, 0);
            }
        }

        if (kt + 1 < NT) {
            _Float16* hn = &hl[(kt + 1) & 1][0];
            *(uint4*)(&hn[c0 * PRH + g0 * 8])        = s0;
            *(uint4*)(&hn[(c0 + 32) * PRH + g0 * 8]) = s1;
        }
        __syncthreads();
    }

    float lA = (lsA0 + lsA1) + (lsA2 + lsA3);
    lA += __shfl_xor(lA, 16, 64);
    lA += __shfl_xor(lA, 32, 64);
    float lB = (lsB0 + lsB1) + (lsB2 + lsB3);
    lB += __shfl_xor(lB, 16, 64);
    lB += __shfl_xor(lB, 32, 64);

    __half* pa = Pacc + (((size_t)(split * 8 + b) * 64) << 12);
#pragma unroll
    for (int cg = 0; cg < 4; cg++)
#pragma unroll
        for (int r = 0; r < 4; r++) {
            int ch = cg * 16 + q * 4 + r;
            pa[((size_t)ch << 12) + colA] = __float2half(accA[cg][r]);
            pa[((size_t)ch << 12) + colB] = __float2half(accB[cg][r]);
        }
    if (q == 0) {
        Lsum[((size_t)(split * 8 + b) << 12) + colA] = lA;
        Lsum[((size_t)(split * 8 + b) << 12) + colB] = lB;
    }
}

// ---------------- merge (R10 form, measured ~4.4us class) --------------------
// grid (64 col-tiles, 8 b, 4 ch-groups of 16), block 256 = 16 ch x 16 col-quads.
template<int S>
__global__ __launch_bounds__(256) void merge_kernel(
    const __half* __restrict__ Pacc, const float* __restrict__ Lsum,
    const float* __restrict__ x, const float* __restrict__ gammap,
    float* __restrict__ out)
{
    __shared__ float invL[64];
    const int tid  = threadIdx.x;
    const int c4   = tid & 15;
    const int chh  = tid >> 4;
    const int b    = blockIdx.y;
    const int col0 = blockIdx.x * 64;
    const int ch   = blockIdx.z * 16 + chh;

    if (tid < 64) {
        float L = 0.f;
#pragma unroll
        for (int s = 0; s < S; s++)
            L += Lsum[((size_t)(s * 8 + b) << 12) + col0 + tid];
        invL[tid] = gammap[0] / L;
    }
    __syncthreads();

    const int cc = c4 * 4;
    const size_t base = (((size_t)b * 64 + ch) << 12) + col0 + cc;
    float4 xv = *(const float4*)(x + base);
    float o0 = 0.f, o1 = 0.f, o2 = 0.f, o3 = 0.f;
#pragma unroll
    for (int s = 0; s < S; s++) {
        half4_t pv = *(const half4_t*)(Pacc +
            (((size_t)(s * 8 + b) * 64 + ch) << 12) + col0 + cc);
        o0 += (float)pv[0];
        o1 += (float)pv[1];
        o2 += (float)pv[2];
        o3 += (float)pv[3];
    }
    float4 ov;
    ov.x = o0 * invL[cc]     + xv.x;
    ov.y = o1 * invL[cc + 1] + xv.y;
    ov.z = o2 * invL[cc + 2] + xv.z;
    ov.w = o3 * invL[cc + 3] + xv.w;
    *(float4*)(out + base) = ov;
}

extern "C" void kernel_launch(void* const* d_in, const int* in_sizes, int n_in,
                              void* d_out, int out_size, void* d_ws, size_t ws_size,
                              hipStream_t stream) {
    const float* x     = (const float*)d_in[0];
    const float* Wq    = (const float*)d_in[1];
    const float* bq    = (const float*)d_in[2];
    const float* Wk    = (const float*)d_in[3];
    const float* bk    = (const float*)d_in[4];
    const float* Wv    = (const float*)d_in[5];
    const float* bv    = (const float*)d_in[6];
    const float* gamma = (const float*)d_in[7];
    float* out = (float*)d_out;

    const size_t fr_bytes  = (size_t)8 * 32768 * 2;             // 512 KB (fTR)
    const size_t g_bytes   = (size_t)8 * NTOK * 16 * 2;         // 1 MB
    const size_t hM_bytes  = (size_t)8 * 64 * NTOK * 2;         // 4 MB
    const size_t pa_split  = (size_t)8 * 64 * NTOK * 2;         // 4 MB per split
    const size_t l_split   = (size_t)8 * NTOK * sizeof(float);  // 128 KB per split
    const size_t base_need = fr_bytes + g_bytes + hM_bytes;

    int S = 1;
    if (ws_size >= base_need + 4 * (pa_split + l_split)) S = 4;
    else if (ws_size >= base_need + 2 * (pa_split + l_split)) S = 2;

    char* p = (char*)d_ws;
    __half* fTR  = (__half*)p;  p += fr_bytes;
    __half* gT16 = (__half*)p;  p += g_bytes;
    __half* hM   = (__half*)p;  p += hM_bytes;
    __half* Pacc = (__half*)p;  p += (size_t)S * pa_split;
    float*  Lsum = (float*)p;

    proj_kernel<<<dim3(64, 8), 320, 0, stream>>>(x, Wq, bq, Wk, bk, Wv, bv,
                                                 fTR, gT16, hM);
    if (S == 4) {
        attn_kernel<16><<<dim3(32, 8, 4), 256, 0, stream>>>(fTR, gT16, hM, Pacc, Lsum);
        merge_kernel<4><<<dim3(64, 8, 4), 256, 0, stream>>>(Pacc, Lsum, x, gamma, out);
    } else if (S == 2) {
        attn_kernel<32><<<dim3(32, 8, 2), 256, 0, stream>>>(fTR, gT16, hM, Pacc, Lsum);
        merge_kernel<2><<<dim3(64, 8, 4), 256, 0, stream>>>(Pacc, Lsum, x, gamma, out);
    } else {
        attn_kernel<64><<<dim3(32, 8, 1), 256, 0, stream>>>(fTR, gT16, hM, Pacc, Lsum);
        merge_kernel<1><<<dim3(64, 8, 4), 256, 0, stream>>>(Pacc, Lsum, x, gamma, out);
    }
}

// Round 13
// 121.057 us; speedup vs baseline: 3.6162x; 1.0017x over previous
//
#include <hip/hip_runtime.h>
#include <hip/hip_fp16.h>

// SelfAttention: B=8, C=64, N=4096, d_head=8.
// o[b,c,m] = gamma * sum_n h[b,c,n] * softmax_n(f[:,n].g[:,m]) + x[b,c,m]
// R13: attn computes l via MFMA ones-row (kills 32 VALU adds/tile + final
// shfls); fTR widened to 4 q-slots (pad constants written by proj) so f-loads
// are unconditional b128s (no exec-mask dance). proj: 2x grid (32-token
// tiles) + XOR-swizzled staging (16-way -> 4-way LDS write conflicts).

typedef _Float16 half8_t __attribute__((ext_vector_type(8)));
typedef _Float16 half4_t __attribute__((ext_vector_type(4)));
typedef _Float16 half2_t __attribute__((ext_vector_type(2)));
typedef __fp16  fp16x2  __attribute__((ext_vector_type(2)));
typedef float float4_t __attribute__((ext_vector_type(4)));

#define NTOK 4096
#define PRH 72   // LDS row stride in halves (144 B: b64 reads 2-way = free)
#define LOG2E 1.44269504088896340736f

#if __has_builtin(__builtin_amdgcn_exp2f)
__device__ __forceinline__ float fexp2(float x) { return __builtin_amdgcn_exp2f(x); }
#else
__device__ __forceinline__ float fexp2(float x) { return exp2f(x); }
#endif

__device__ __forceinline__ half2_t pkcvt(float a, float b) {
    fp16x2 v = __builtin_amdgcn_cvt_pkrtz(a, b);
    return __builtin_bit_cast(half2_t, v);
}

// ---------------- projection (MFMA) ------------------------------------------
// grid (128 token-tiles of 32, 8 b), block 320 = 5 waves = 5 out-row-groups.
// wave0 rows = Wq(8)+Wk(8); waves1-4 = Wv rows. x staged transposed to LDS
// fp16 with XOR channel swizzle (write conflicts 16-way -> 4-way).
// fTR records: [b][kt64*16+ml][q 0..3][t4][4] halves (128 B); q>=2 slots are
// the K-pad constants so attn loads unconditionally.
__global__ __launch_bounds__(320) void proj_kernel(
    const float* __restrict__ x,
    const float* __restrict__ Wq, const float* __restrict__ bq,
    const float* __restrict__ Wk, const float* __restrict__ bk,
    const float* __restrict__ Wv, const float* __restrict__ bv,
    __half* __restrict__ fTR, __half* __restrict__ gT16, __half* __restrict__ hM)
{
    __shared__ __align__(16) _Float16 xh[32 * PRH];   // 4.6 KB
    const int t      = threadIdx.x;
    const int blk    = blockIdx.x;
    const int b      = blockIdx.y;
    const int n0     = blk * 32;
    const int kt64   = blk >> 1;
    const int t4base = (blk & 1) * 2;

    // stage x[b][c][n0..+31] -> xh[tok][c ^ swz] fp16
    if (t < 256) {
#pragma unroll
        for (int i = 0; i < 2; i++) {
            const int idx = t + i * 256;
            const int c = idx >> 3, f4 = idx & 7;          // tokens f4*4..+3
            float4 v = *(const float4*)(x + (((size_t)(b * 64 + c)) << 12) + n0 + f4 * 4);
            const int cs = c ^ ((f4 & 3) << 4);
            xh[(f4 * 4 + 0) * PRH + cs] = (_Float16)v.x;
            xh[(f4 * 4 + 1) * PRH + cs] = (_Float16)v.y;
            xh[(f4 * 4 + 2) * PRH + cs] = (_Float16)v.z;
            xh[(f4 * 4 + 3) * PRH + cs] = (_Float16)v.w;
        }
    }

    const int w    = t >> 6;
    const int lane = t & 63;
    const int q    = lane >> 4;
    const int ml   = lane & 15;

    // A-frags: W row, k = ks*16 + q*4 + j
    const float* wrow;
    if (w == 0) wrow = (ml < 8) ? (Wq + ml * 64) : (Wk + (ml - 8) * 64);
    else        wrow = Wv + ((w - 1) * 16 + ml) * 64;
    half4_t afr[4];
#pragma unroll
    for (int ks = 0; ks < 4; ks++) {
        float4 wv4 = *(const float4*)(wrow + ks * 16 + q * 4);
        afr[ks] = (half4_t){(_Float16)wv4.x, (_Float16)wv4.y,
                            (_Float16)wv4.z, (_Float16)wv4.w};
    }
    float4 bias4;
    if (w == 0) bias4 = (q < 2) ? *(const float4*)(bq + q * 4)
                                : *(const float4*)(bk + (q - 2) * 4);
    else        bias4 = *(const float4*)(bv + (w - 1) * 16 + q * 4);

    __syncthreads();

#pragma unroll
    for (int cg = 0; cg < 2; cg++) {
        const int tok  = cg * 16 + ml;                  // local token
        const int swz  = (tok >> 2) & 3;
        float4_t acc = (float4_t){0.f, 0.f, 0.f, 0.f};
#pragma unroll
        for (int ks = 0; ks < 4; ks++) {
            half4_t bfr = *(const half4_t*)(&xh[tok * PRH + ((ks ^ swz) * 16 + q * 4)]);
            acc = __builtin_amdgcn_mfma_f32_16x16x16f16(afr[ks], bfr, acc, 0, 0, 0);
        }
        acc[0] += bias4.x; acc[1] += bias4.y; acc[2] += bias4.z; acc[3] += bias4.w;
        const int gtok = n0 + tok;
        const int t4   = t4base + cg;

        if (w == 0) {
            __half* rec = fTR + ((size_t)b << 16) + (size_t)(kt64 * 16 + ml) * 64;
            if (q < 2) {
                half4_t fv = {(_Float16)(acc[0] * LOG2E), (_Float16)(acc[1] * LOG2E),
                              (_Float16)(acc[2] * LOG2E), (_Float16)(acc[3] * LOG2E)};
                *(half4_t*)(rec + q * 16 + t4 * 4) = fv;
            } else {
                // constant K-pad slots: q2 = {1,0,0,0}, q3 = zeros
                half4_t cv = (half4_t){};
                if (q == 2) cv[0] = (_Float16)1.0f;
                *(half4_t*)(rec + q * 16 + t4 * 4) = cv;
            }
            // g rows live in q>=2 lanes; gn2 via xor16 pairing (q2<->q3)
            float gn2p = acc[0] * acc[0] + acc[1] * acc[1] +
                         acc[2] * acc[2] + acc[3] * acc[3];
            float gn2 = gn2p + __shfl_xor(gn2p, 16, 64);
            if (q >= 2) {
                half4_t gv = {(_Float16)acc[0], (_Float16)acc[1],
                              (_Float16)acc[2], (_Float16)acc[3]};
                __half* gp = gT16 + (size_t)((b << 12) + gtok) * 16;
                *(half4_t*)(gp + (q - 2) * 4) = gv;
                if (q == 2) {
                    const float M = (LOG2E * 4.6f) * __builtin_sqrtf(gn2) + 1.0f;
                    *(half4_t*)(gp + 8) = (half4_t){(_Float16)(-M), 0, 0, 0};
                } else {
                    *(half4_t*)(gp + 12) = (half4_t){};
                }
            }
        } else {
            const int ch = (w - 1) * 16 + q * 4;
#pragma unroll
            for (int r = 0; r < 4; r++)
                hM[(((size_t)b * 64 + ch + r) << 12) + gtok] = __float2half(acc[r]);
        }
    }
}

// ---------------- fused flash attention (key-split, shifted softmax) ---------
// grid (32 colblocks of 128, 8 b, S), block 256 = 4 waves x 32 cols (2 groups).
// l computed by MFMA ones-row; f-records loaded unconditionally (pad in ws).
template<int NT>
__global__ __launch_bounds__(256) void attn_kernel(
    const __half* __restrict__ fTR, const __half* __restrict__ gT16,
    const __half* __restrict__ hM,
    __half* __restrict__ Pacc, float* __restrict__ Lsum)
{
    __shared__ __align__(16) _Float16 hl[2][64 * PRH];  // 2 x 9216 B
    const int tid   = threadIdx.x;
    const int w     = tid >> 6;
    const int lane  = tid & 63;
    const int q     = lane >> 4;
    const int ml    = lane & 15;
    const int b     = blockIdx.y;
    const int split = blockIdx.z;
    const int colA  = blockIdx.x * 128 + w * 16 + ml;
    const int colB  = colA + 64;

    half4_t gfA = *(const half4_t*)(gT16 + ((size_t)((b << 12) + colA)) * 16 + q * 4);
    half4_t gfB = *(const half4_t*)(gT16 + ((size_t)((b << 12) + colB)) * 16 + q * 4);

    float4_t accA[4], accB[4];
#pragma unroll
    for (int cg = 0; cg < 4; cg++) {
        accA[cg] = (float4_t){0.f, 0.f, 0.f, 0.f};
        accB[cg] = (float4_t){0.f, 0.f, 0.f, 0.f};
    }
    float4_t accLA = (float4_t){0.f, 0.f, 0.f, 0.f};
    float4_t accLB = (float4_t){0.f, 0.f, 0.f, 0.f};
    const half4_t onesf = {(_Float16)1.0f, (_Float16)1.0f,
                           (_Float16)1.0f, (_Float16)1.0f};

    const int kt0 = split * NT;
    const int c0  = tid >> 3;
    const int g0  = tid & 7;

    const __half* srow0 = hM + ((size_t)(b * 64 + c0) << 12) + kt0 * 64 + g0 * 8;
    const __half* srow1 = srow0 + ((size_t)32 << 12);
    const __half* fptr  = fTR + ((size_t)b << 16) + (size_t)(kt0 * 16 + ml) * 64 + q * 16;

    // ---- prologue: stage tile 0 + load f record (2 x b128, unconditional) ----
    uint4 s0 = *(const uint4*)srow0;
    uint4 s1 = *(const uint4*)srow1;
    half8_t f01 = *(const half8_t*)fptr;
    half8_t f23 = *(const half8_t*)(fptr + 8);
    *(uint4*)(&hl[0][c0 * PRH + g0 * 8])        = s0;
    *(uint4*)(&hl[0][(c0 + 32) * PRH + g0 * 8]) = s1;
    __syncthreads();

#pragma unroll 1
    for (int kt = 0; kt < NT; kt++) {
        const _Float16* hbL = &hl[kt & 1][ml * PRH + q * 4];
        half4_t afn0 = __builtin_shufflevector(f01, f01, 0, 1, 2, 3);
        half4_t afn1 = __builtin_shufflevector(f01, f01, 4, 5, 6, 7);
        half4_t afn2 = __builtin_shufflevector(f23, f23, 0, 1, 2, 3);
        half4_t afn3 = __builtin_shufflevector(f23, f23, 4, 5, 6, 7);

        float4_t stA0 = __builtin_amdgcn_mfma_f32_16x16x16f16(
            afn0, gfA, (float4_t){0.f, 0.f, 0.f, 0.f}, 0, 0, 0);
        float4_t stA1 = __builtin_amdgcn_mfma_f32_16x16x16f16(
            afn1, gfA, (float4_t){0.f, 0.f, 0.f, 0.f}, 0, 0, 0);
        float4_t stA2 = __builtin_amdgcn_mfma_f32_16x16x16f16(
            afn2, gfA, (float4_t){0.f, 0.f, 0.f, 0.f}, 0, 0, 0);
        float4_t stA3 = __builtin_amdgcn_mfma_f32_16x16x16f16(
            afn3, gfA, (float4_t){0.f, 0.f, 0.f, 0.f}, 0, 0, 0);
        float4_t stB0 = __builtin_amdgcn_mfma_f32_16x16x16f16(
            afn0, gfB, (float4_t){0.f, 0.f, 0.f, 0.f}, 0, 0, 0);
        float4_t stB1 = __builtin_amdgcn_mfma_f32_16x16x16f16(
            afn1, gfB, (float4_t){0.f, 0.f, 0.f, 0.f}, 0, 0, 0);
        float4_t stB2 = __builtin_amdgcn_mfma_f32_16x16x16f16(
            afn2, gfB, (float4_t){0.f, 0.f, 0.f, 0.f}, 0, 0, 0);
        float4_t stB3 = __builtin_amdgcn_mfma_f32_16x16x16f16(
            afn3, gfB, (float4_t){0.f, 0.f, 0.f, 0.f}, 0, 0, 0);

        // ---- prefetch next tile ----
        if (kt + 1 < NT) {
            f01 = *(const half8_t*)(fptr + 1024);
            f23 = *(const half8_t*)(fptr + 1032);
            s0 = *(const uint4*)(srow0 + 64);
            s1 = *(const uint4*)(srow1 + 64);
            fptr  += 1024;
            srow0 += 64;
            srow1 += 64;
        }

        // ---- exp + PV per 16-key group; l via ones-MFMA ----
        {
            float pA0 = fexp2(stA0[0]), pA1 = fexp2(stA0[1]),
                  pA2 = fexp2(stA0[2]), pA3 = fexp2(stA0[3]);
            float pB0 = fexp2(stB0[0]), pB1 = fexp2(stB0[1]),
                  pB2 = fexp2(stB0[2]), pB3 = fexp2(stB0[3]);
            half2_t a_lo = pkcvt(pA0, pA1), a_hi = pkcvt(pA2, pA3);
            half2_t b_lo = pkcvt(pB0, pB1), b_hi = pkcvt(pB2, pB3);
            half4_t pfA = {a_lo[0], a_lo[1], a_hi[0], a_hi[1]};
            half4_t pfB = {b_lo[0], b_lo[1], b_hi[0], b_hi[1]};
            accLA = __builtin_amdgcn_mfma_f32_16x16x16f16(onesf, pfA, accLA, 0, 0, 0);
            accLB = __builtin_amdgcn_mfma_f32_16x16x16f16(onesf, pfB, accLB, 0, 0, 0);
#pragma unroll
            for (int cg = 0; cg < 4; cg++) {
                half4_t ah = *(const half4_t*)(hbL + cg * (16 * PRH) + 0 * 16);
                accA[cg] = __builtin_amdgcn_mfma_f32_16x16x16f16(ah, pfA, accA[cg], 0, 0, 0);
                accB[cg] = __builtin_amdgcn_mfma_f32_16x16x16f16(ah, pfB, accB[cg], 0, 0, 0);
            }
        }
        {
            float pA0 = fexp2(stA1[0]), pA1 = fexp2(stA1[1]),
                  pA2 = fexp2(stA1[2]), pA3 = fexp2(stA1[3]);
            float pB0 = fexp2(stB1[0]), pB1 = fexp2(stB1[1]),
                  pB2 = fexp2(stB1[2]), pB3 = fexp2(stB1[3]);
            half2_t a_lo = pkcvt(pA0, pA1), a_hi = pkcvt(pA2, pA3);
            half2_t b_lo = pkcvt(pB0, pB1), b_hi = pkcvt(pB2, pB3);
            half4_t pfA = {a_lo[0], a_lo[1], a_hi[0], a_hi[1]};
            half4_t pfB = {b_lo[0], b_lo[1], b_hi[0], b_hi[1]};
            accLA = __builtin_amdgcn_mfma_f32_16x16x16f16(onesf, pfA, accLA, 0, 0, 0);
            accLB = __builtin_amdgcn_mfma_f32_16x16x16f16(onesf, pfB, accLB, 0, 0, 0);
#pragma unroll
            for (int cg = 0; cg < 4; cg++) {
                half4_t ah = *(const half4_t*)(hbL + cg * (16 * PRH) + 1 * 16);
                accA[cg] = __builtin_amdgcn_mfma_f32_16x16x16f16(ah, pfA, accA[cg], 0, 0, 0);
                accB[cg] = __builtin_amdgcn_mfma_f32_16x16x16f16(ah, pfB, accB[cg], 0, 0, 0);
            }
        }
        {
            float pA0 = fexp2(stA2[0]), pA1 = fexp2(stA2[1]),
                  pA2 = fexp2(stA2[2]), pA3 = fexp2(stA2[3]);
            float pB0 = fexp2(stB2[0]), pB1 = fexp2(stB2[1]),
                  pB2 = fexp2(stB2[2]), pB3 = fexp2(stB2[3]);
            half2_t a_lo = pkcvt(pA0, pA1), a_hi = pkcvt(pA2, pA3);
            half2_t b_lo = pkcvt(pB0, pB1), b_hi = pkcvt(pB2, pB3);
            half4_t pfA = {a_lo[0], a_lo[1], a_hi[0], a_hi[1]};
            half4_t pfB = {b_lo[0], b_lo[1], b_hi[0], b_hi[1]};
            accLA = __builtin_amdgcn_mfma_f32_16x16x16f16(onesf, pfA, accLA, 0, 0, 0);
            accLB = __builtin_amdgcn_mfma_f32_16x16x16f16(onesf, pfB, accLB, 0, 0, 0);
#pragma unroll
            for (int cg = 0; cg < 4; cg++) {
                half4_t ah = *(const half4_t*)(hbL + cg * (16 * PRH) + 2 * 16);
                accA[cg] = __builtin_amdgcn_mfma_f32_16x16x16f16(ah, pfA, accA[cg], 0, 0, 0);
                accB[cg] = __builtin_amdgcn_mfma_f32_16x16x16f16(ah, pfB, accB[cg], 0, 0, 0);
            }
        }
        {
            float pA0 = fexp2(stA3[0]), pA1 = fexp2(stA3[1]),
                  pA2 = fexp2(stA3[2]), pA3 = fexp2(stA3[3]);
            float pB0 = fexp2(stB3[0]), pB1 = fexp2(stB3[1]),
                  pB2 = fexp2(stB3[2]), pB3 = fexp2(stB3[3]);
            half2_t a_lo = pkcvt(pA0, pA1), a_hi = pkcvt(pA2, pA3);
            half2_t b_lo = pkcvt(pB0, pB1), b_hi = pkcvt(pB2, pB3);
            half4_t pfA = {a_lo[0], a_lo[1], a_hi[0], a_hi[1]};
            half4_t pfB = {b_lo[0], b_lo[1], b_hi[0], b_hi[1]};
            accLA = __builtin_amdgcn_mfma_f32_16x16x16f16(onesf, pfA, accLA, 0, 0, 0);
            accLB = __builtin_amdgcn_mfma_f32_16x16x16f16(onesf, pfB, accLB, 0, 0, 0);
#pragma unroll
            for (int cg = 0; cg < 4; cg++) {
                half4_t ah = *(const half4_t*)(hbL + cg * (16 * PRH) + 3 * 16);
                accA[cg] = __builtin_amdgcn_mfma_f32_16x16x16f16(ah, pfA, accA[cg], 0, 0, 0);
                accB[cg] = __builtin_amdgcn_mfma_f32_16x16x16f16(ah, pfB, accB[cg], 0, 0, 0);
            }
        }

        if (kt + 1 < NT) {
            _Float16* hn = &hl[(kt + 1) & 1][0];
            *(uint4*)(&hn[c0 * PRH + g0 * 8])        = s0;
            *(uint4*)(&hn[(c0 + 32) * PRH + g0 * 8]) = s1;
        }
        __syncthreads();
    }

    // ---- store UNNORMALIZED partials + l (from ones-MFMA accumulator) ----
    __half* pa = Pacc + (((size_t)(split * 8 + b) * 64) << 12);
#pragma unroll
    for (int cg = 0; cg < 4; cg++)
#pragma unroll
        for (int r = 0; r < 4; r++) {
            int ch = cg * 16 + q * 4 + r;
            pa[((size_t)ch << 12) + colA] = __float2half(accA[cg][r]);
            pa[((size_t)ch << 12) + colB] = __float2half(accB[cg][r]);
        }
    if (q == 0) {
        Lsum[((size_t)(split * 8 + b) << 12) + colA] = accLA[0];
        Lsum[((size_t)(split * 8 + b) << 12) + colB] = accLB[0];
    }
}

// ---------------- merge ------------------------------------------------------
// grid (64 col-tiles, 8 b, 4 ch-groups of 16), block 256 = 16 ch x 16 col-quads.
template<int S>
__global__ __launch_bounds__(256) void merge_kernel(
    const __half* __restrict__ Pacc, const float* __restrict__ Lsum,
    const float* __restrict__ x, const float* __restrict__ gammap,
    float* __restrict__ out)
{
    __shared__ float invL[64];
    const int tid  = threadIdx.x;
    const int c4   = tid & 15;
    const int chh  = tid >> 4;
    const int b    = blockIdx.y;
    const int col0 = blockIdx.x * 64;
    const int ch   = blockIdx.z * 16 + chh;

    if (tid < 64) {
        float L = 0.f;
#pragma unroll
        for (int s = 0; s < S; s++)
            L += Lsum[((size_t)(s * 8 + b) << 12) + col0 + tid];
        invL[tid] = gammap[0] / L;
    }
    __syncthreads();

    const int cc = c4 * 4;
    const size_t base = (((size_t)b * 64 + ch) << 12) + col0 + cc;
    float4 xv = *(const float4*)(x + base);
    float o0 = 0.f, o1 = 0.f, o2 = 0.f, o3 = 0.f;
#pragma unroll
    for (int s = 0; s < S; s++) {
        half4_t pv = *(const half4_t*)(Pacc +
            (((size_t)(s * 8 + b) * 64 + ch) << 12) + col0 + cc);
        o0 += (float)pv[0];
        o1 += (float)pv[1];
        o2 += (float)pv[2];
        o3 += (float)pv[3];
    }
    float4 ov;
    ov.x = o0 * invL[cc]     + xv.x;
    ov.y = o1 * invL[cc + 1] + xv.y;
    ov.z = o2 * invL[cc + 2] + xv.z;
    ov.w = o3 * invL[cc + 3] + xv.w;
    *(float4*)(out + base) = ov;
}

extern "C" void kernel_launch(void* const* d_in, const int* in_sizes, int n_in,
                              void* d_out, int out_size, void* d_ws, size_t ws_size,
                              hipStream_t stream) {
    const float* x     = (const float*)d_in[0];
    const float* Wq    = (const float*)d_in[1];
    const float* bq    = (const float*)d_in[2];
    const float* Wk    = (const float*)d_in[3];
    const float* bk    = (const float*)d_in[4];
    const float* Wv    = (const float*)d_in[5];
    const float* bv    = (const float*)d_in[6];
    const float* gamma = (const float*)d_in[7];
    float* out = (float*)d_out;

    const size_t fr_bytes  = (size_t)8 * 65536 * 2;             // 1 MB (fTR, 4 q-slots)
    const size_t g_bytes   = (size_t)8 * NTOK * 16 * 2;         // 1 MB
    const size_t hM_bytes  = (size_t)8 * 64 * NTOK * 2;         // 4 MB
    const size_t pa_split  = (size_t)8 * 64 * NTOK * 2;         // 4 MB per split
    const size_t l_split   = (size_t)8 * NTOK * sizeof(float);  // 128 KB per split
    const size_t base_need = fr_bytes + g_bytes + hM_bytes;

    int S = 1;
    if (ws_size >= base_need + 4 * (pa_split + l_split)) S = 4;
    else if (ws_size >= base_need + 2 * (pa_split + l_split)) S = 2;

    char* p = (char*)d_ws;
    __half* fTR  = (__half*)p;  p += fr_bytes;
    __half* gT16 = (__half*)p;  p += g_bytes;
    __half* hM   = (__half*)p;  p += hM_bytes;
    __half* Pacc = (__half*)p;  p += (size_t)S * pa_split;
    float*  Lsum = (float*)p;

    proj_kernel<<<dim3(128, 8), 320, 0, stream>>>(x, Wq, bq, Wk, bk, Wv, bv,
                                                  fTR, gT16, hM);
    if (S == 4) {
        attn_kernel<16><<<dim3(32, 8, 4), 256, 0, stream>>>(fTR, gT16, hM, Pacc, Lsum);
        merge_kernel<4><<<dim3(64, 8, 4), 256, 0, stream>>>(Pacc, Lsum, x, gamma, out);
    } else if (S == 2) {
        attn_kernel<32><<<dim3(32, 8, 2), 256, 0, stream>>>(fTR, gT16, hM, Pacc, Lsum);
        merge_kernel<2><<<dim3(64, 8, 4), 256, 0, stream>>>(Pacc, Lsum, x, gamma, out);
    } else {
        attn_kernel<64><<<dim3(32, 8, 1), 256, 0, stream>>>(fTR, gT16, hM, Pacc, Lsum);
        merge_kernel<1><<<dim3(64, 8, 4), 256, 0, stream>>>(Pacc, Lsum, x, gamma, out);
    }
}